// Round 5
// baseline (567.506 us; speedup 1.0000x reference)
//
#include <hip/hip_runtime.h>
#include <hip/hip_bf16.h>

#define N_NODES 100000
#define N_EDGES 600000
#define NB      512
#define H       128
#define ED      8
#define SCAN_CHUNK 1024
#define N_CHUNKS   98   // 98*1024 = 100352 >= N_NODES+1

typedef __attribute__((ext_vector_type(8))) short short8;
typedef __attribute__((ext_vector_type(4))) float f32x4;
typedef __attribute__((ext_vector_type(4))) unsigned int u32x4;
typedef unsigned short u16;
typedef unsigned int   u32;

static __device__ __forceinline__ u16 f2bf(float f) {
    u32 u = __float_as_uint(f);
    u32 r = u + 0x7fffu + ((u >> 16) & 1u);
    return (u16)(r >> 16);
}
static __device__ __forceinline__ float bf2f(u32 h) {
    return __uint_as_float(h << 16);
}

// ---- weight pack (ALL matrices in one launch) -----------------------------
__global__ __launch_bounds__(256) void pack_all_kernel(
    const float* __restrict__ W0, const float* __restrict__ W1,
    const float* __restrict__ W2, const float* __restrict__ W3,
    const float* __restrict__ W4, const float* __restrict__ W5,
    const float* __restrict__ W6,
    short8* __restrict__ O0, short8* __restrict__ O1,
    short8* __restrict__ O2, short8* __restrict__ O3,
    short8* __restrict__ O4, short8* __restrict__ O5,
    short8* __restrict__ O6)
{
    int gid = blockIdx.x * 256 + threadIdx.x;
    const int total = 512 + 6 * 2048;
    if (gid >= total) return;
    const float* W; short8* O; int Krows, kkmax, slot;
    if (gid < 512) { W = W0; O = O0; Krows = ED; kkmax = 1; slot = gid; }
    else {
        int m = (gid - 512) / 2048;
        slot = (gid - 512) % 2048;
        Krows = H; kkmax = 4;
        switch (m) {
            case 0: W = W1; O = O1; break;
            case 1: W = W2; O = O2; break;
            case 2: W = W3; O = O3; break;
            case 3: W = W4; O = O4; break;
            case 4: W = W5; O = O5; break;
            default: W = W6; O = O6; break;
        }
    }
    int lane = slot & 63;
    int t = slot >> 6;
    int nt = t & 1; t >>= 1;
    int kk = t % kkmax;
    int w  = t / kkmax;
    int quad = lane >> 4, n15 = lane & 15;
    int n = w * 32 + nt * 16 + n15;
    short8 v;
    #pragma unroll
    for (int j = 0; j < 8; j++) {
        int k = kk * 32 + quad * 8 + j;
        v[j] = (k < Krows) ? (short)f2bf(W[k * H + n]) : (short)0;
    }
    O[slot] = v;
}

// ---------------- CSR build ------------------------------------------------
__global__ __launch_bounds__(256) void hist_kernel(
    const int* __restrict__ edge_index, int* __restrict__ counts)
{
    int e = blockIdx.x * 256 + threadIdx.x;
    if (e < N_EDGES) atomicAdd(&counts[edge_index[N_EDGES + e]], 1);
}

__global__ __launch_bounds__(SCAN_CHUNK) void scan1_kernel(
    const int* __restrict__ counts, int* __restrict__ chunk_scan,
    int* __restrict__ bsum_raw)
{
    __shared__ int s[SCAN_CHUNK];
    int tid = threadIdx.x;
    int gid = blockIdx.x * SCAN_CHUNK + tid;
    int v = counts[gid];
    s[tid] = v;
    __syncthreads();
    #pragma unroll
    for (int off = 1; off < SCAN_CHUNK; off <<= 1) {
        int t = (tid >= off) ? s[tid - off] : 0;
        __syncthreads();
        s[tid] += t;
        __syncthreads();
    }
    chunk_scan[gid] = s[tid] - v;
    if (tid == SCAN_CHUNK - 1) bsum_raw[blockIdx.x] = s[tid];
}

__global__ __launch_bounds__(128) void scan2_kernel(
    const int* __restrict__ bsum_raw, int* __restrict__ bsum_scan)
{
    __shared__ int s[128];
    int tid = threadIdx.x;
    int v = (tid < N_CHUNKS) ? bsum_raw[tid] : 0;
    s[tid] = v;
    __syncthreads();
    #pragma unroll
    for (int off = 1; off < 128; off <<= 1) {
        int t = (tid >= off) ? s[tid - off] : 0;
        __syncthreads();
        s[tid] += t;
        __syncthreads();
    }
    bsum_scan[tid] = s[tid] - v;
}

// fill: src_list[pos]=src (CSR order); attr_perm[pos]=bf16(attr[e]) (CSR order)
__global__ __launch_bounds__(256) void fill_kernel(
    const int* __restrict__ edge_index,
    const int* __restrict__ chunk_scan, const int* __restrict__ bsum_scan,
    int* __restrict__ counts, int* __restrict__ src_list,
    const float* __restrict__ attr, u16* __restrict__ attr_perm)
{
    int e = blockIdx.x * 256 + threadIdx.x;
    if (e >= N_EDGES) return;
    int src = edge_index[e];
    int dst = edge_index[N_EDGES + e];
    int slot = atomicAdd(&counts[dst], -1) - 1;
    int pos = chunk_scan[dst] + bsum_scan[dst >> 10] + slot;
    src_list[pos] = src;
    float4 v0 = *(const float4*)&attr[(long)e * ED];
    float4 v1 = *(const float4*)&attr[(long)e * ED + 4];
    u32 w0 = (u32)f2bf(v0.x) | ((u32)f2bf(v0.y) << 16);
    u32 w1 = (u32)f2bf(v0.z) | ((u32)f2bf(v0.w) << 16);
    u32 w2 = (u32)f2bf(v1.x) | ((u32)f2bf(v1.y) << 16);
    u32 w3 = (u32)f2bf(v1.z) | ((u32)f2bf(v1.w) << 16);
    *(uint4*)&attr_perm[(long)pos * ED] = make_uint4(w0, w1, w2, w3);
}

// row_start[n] = chunk_scan[n] + bsum_scan[n>>10]   (n in [0, N])
__global__ __launch_bounds__(256) void finalize_offsets(
    const int* __restrict__ chunk_scan, const int* __restrict__ bsum_scan,
    int* __restrict__ row_start)
{
    int i = blockIdx.x * 256 + threadIdx.x;
    if (i <= N_NODES) row_start[i] = chunk_scan[i] + bsum_scan[i >> 10];
}

// ---------------- node MLP (MFMA layer2): x bf16 [N,H] ---------------------
__global__ __launch_bounds__(256) void node_mlp_mfma(
    const int* __restrict__ ids,
    const float* __restrict__ w1, const float* __restrict__ b1,
    const short8* __restrict__ pW2, const float* __restrict__ b2,
    u16* __restrict__ x_out)
{
    __shared__ u16 sH[64 * 136];
    __shared__ float s_x0[64];
    int tid = threadIdx.x;
    int w = tid >> 6, lane = tid & 63, quad = lane >> 4, n15 = lane & 15;
    short8 fW2[4][2];
    #pragma unroll
    for (int kk = 0; kk < 4; kk++) {
        fW2[kk][0] = pW2[((w * 4 + kk) * 2 + 0) * 64 + lane];
        fW2[kk][1] = pW2[((w * 4 + kk) * 2 + 1) * 64 + lane];
    }
    float rb2[2] = { b2[w * 32 + n15], b2[w * 32 + 16 + n15] };
    float w1c = w1[tid & 127], b1c = b1[tid & 127];
    const int ntile = (N_NODES + 63) / 64;
    for (int tile = blockIdx.x; tile < ntile; tile += gridDim.x) {
        int row0 = tile * 64;
        if (tid < 64) {
            int n = row0 + tid;
            float x0 = (n < N_NODES) ? (float)ids[n] / 281474976710655.0f : 0.0f;
            s_x0[tid] = fminf(fmaxf(x0, 0.0f), 1.0f);
        }
        __syncthreads();
        int half = tid >> 7, c = tid & 127;
        #pragma unroll 8
        for (int rr = 0; rr < 32; rr++) {
            int r = half + rr * 2;
            sH[r * 136 + c] = f2bf(fmaxf(s_x0[r] * w1c + b1c, 0.0f));
        }
        __syncthreads();
        f32x4 acc[4][2];
        #pragma unroll
        for (int s = 0; s < 4; s++) { acc[s][0] = (f32x4){0,0,0,0}; acc[s][1] = (f32x4){0,0,0,0}; }
        #pragma unroll
        for (int kk = 0; kk < 4; kk++) {
            #pragma unroll
            for (int s = 0; s < 4; s++) {
                short8 a = *(const short8*)&sH[(s * 16 + n15) * 136 + kk * 32 + quad * 8];
                acc[s][0] = __builtin_amdgcn_mfma_f32_16x16x32_bf16(a, fW2[kk][0], acc[s][0], 0, 0, 0);
                acc[s][1] = __builtin_amdgcn_mfma_f32_16x16x32_bf16(a, fW2[kk][1], acc[s][1], 0, 0, 0);
            }
        }
        __syncthreads();
        #pragma unroll
        for (int s = 0; s < 4; s++)
            #pragma unroll
            for (int nt = 0; nt < 2; nt++) {
                int col = w * 32 + nt * 16 + n15;
                #pragma unroll
                for (int reg = 0; reg < 4; reg++)
                    sH[(s * 16 + quad * 4 + reg) * 136 + col] =
                        f2bf(acc[s][nt][reg] + rb2[nt]);
            }
        __syncthreads();
        for (int idx = tid; idx < 64 * 16; idx += 256) {
            int r = idx >> 4, c8 = (idx & 15) << 3;
            int n = row0 + r;
            if (n < N_NODES)
                *(uint4*)&x_out[(long)n * H + c8] = *(const uint4*)&sH[r * 136 + c8];
        }
        __syncthreads();
    }
}

// ---- fused message pass: recompute e from attr + gather x + aggregate -----
// tile = 32 nodes (3125 blocks exact). Per 64-CSR-position chunk:
//   stage attr+src -> edge-MLP GEMM1/GEMM2 (e in LDS) -> 16-lane groups
//   (2 contiguous nodes each) gather x[src], add e, relu, accumulate f32.
// e is recomputed bit-identically in both conv passes (same pack/pipeline).
__global__ __launch_bounds__(256) void gine_msg_fused(
    const int* __restrict__ row_start,
    const int* __restrict__ src_list,
    const u16* __restrict__ attr_perm,
    const u16* __restrict__ x,
    const short8* __restrict__ pW1, const float* __restrict__ b1,
    const short8* __restrict__ pW2, const float* __restrict__ b2,
    u16* __restrict__ xs_out)
{
    __shared__ u16 sA[64 * 40];
    __shared__ u16 sH[64 * 136];
    __shared__ int sSrc[64];
    int tid = threadIdx.x;
    int w = tid >> 6, lane = tid & 63, quad = lane >> 4, n15 = lane & 15;
    short8 fW1[2];
    fW1[0] = pW1[(w * 2 + 0) * 64 + lane];
    fW1[1] = pW1[(w * 2 + 1) * 64 + lane];
    short8 fW2[4][2];
    #pragma unroll
    for (int kk = 0; kk < 4; kk++) {
        fW2[kk][0] = pW2[((w * 4 + kk) * 2 + 0) * 64 + lane];
        fW2[kk][1] = pW2[((w * 4 + kk) * 2 + 1) * 64 + lane];
    }
    float rb1[2] = { b1[w * 32 + n15], b1[w * 32 + 16 + n15] };
    float rb2[2] = { b2[w * 32 + n15], b2[w * 32 + 16 + n15] };
    // zero K-pad cols 8..31 of sA once (never overwritten after)
    for (int idx = tid; idx < 64 * 3; idx += 256) {
        int r = idx / 3, c8 = 8 + (idx % 3) * 8;
        *(uint4*)&sA[r * 40 + c8] = make_uint4(0, 0, 0, 0);
    }
    int gid = tid >> 4, l16 = tid & 15, fo = l16 * 8;
    int nd0 = blockIdx.x * 32;
    int nA   = nd0 + gid * 2;
    int begA = row_start[nA];
    int endA = row_start[nA + 1];
    int endB = row_start[nA + 2];
    int p0   = row_start[nd0];
    int pEnd = row_start[nd0 + 32];
    const u16* xb = x + fo;
    float a[8], b[8];
    #pragma unroll
    for (int q = 0; q < 8; q++) { a[q] = 0.0f; b[q] = 0.0f; }

    for (int c0 = p0; c0 < pEnd; c0 += 64) {
        int cnt = min(64, pEnd - c0);
        int ce  = c0 + cnt;
        // stage src + attr rows for this chunk
        if (tid < 64) {
            if (tid < cnt) sSrc[tid] = src_list[c0 + tid];
        } else if (tid < 128) {
            int r = tid - 64;
            if (r < cnt)
                *(uint4*)&sA[r * 40] = *(const uint4*)&attr_perm[(long)(c0 + r) * ED];
        }
        __syncthreads();
        // GEMM1 (K=32, attr in cols 0..7, zero pad 8..31)
        f32x4 acc[4][2];
        #pragma unroll
        for (int s = 0; s < 4; s++) { acc[s][0] = (f32x4){0,0,0,0}; acc[s][1] = (f32x4){0,0,0,0}; }
        #pragma unroll
        for (int s = 0; s < 4; s++) {
            short8 av = *(const short8*)&sA[(s * 16 + n15) * 40 + quad * 8];
            acc[s][0] = __builtin_amdgcn_mfma_f32_16x16x32_bf16(av, fW1[0], acc[s][0], 0, 0, 0);
            acc[s][1] = __builtin_amdgcn_mfma_f32_16x16x32_bf16(av, fW1[1], acc[s][1], 0, 0, 0);
        }
        #pragma unroll
        for (int s = 0; s < 4; s++)
            #pragma unroll
            for (int nt = 0; nt < 2; nt++) {
                int col = w * 32 + nt * 16 + n15;
                #pragma unroll
                for (int reg = 0; reg < 4; reg++)
                    sH[(s * 16 + quad * 4 + reg) * 136 + col] =
                        f2bf(fmaxf(acc[s][nt][reg] + rb1[nt], 0.0f));
            }
        __syncthreads();
        // GEMM2 (K=128)
        #pragma unroll
        for (int s = 0; s < 4; s++) { acc[s][0] = (f32x4){0,0,0,0}; acc[s][1] = (f32x4){0,0,0,0}; }
        #pragma unroll
        for (int kk = 0; kk < 4; kk++) {
            #pragma unroll
            for (int s = 0; s < 4; s++) {
                short8 av = *(const short8*)&sH[(s * 16 + n15) * 136 + kk * 32 + quad * 8];
                acc[s][0] = __builtin_amdgcn_mfma_f32_16x16x32_bf16(av, fW2[kk][0], acc[s][0], 0, 0, 0);
                acc[s][1] = __builtin_amdgcn_mfma_f32_16x16x32_bf16(av, fW2[kk][1], acc[s][1], 0, 0, 0);
            }
        }
        __syncthreads();   // all sH (hidden) reads done
        // write e tile (bias, NO relu) into sH
        #pragma unroll
        for (int s = 0; s < 4; s++)
            #pragma unroll
            for (int nt = 0; nt < 2; nt++) {
                int col = w * 32 + nt * 16 + n15;
                #pragma unroll
                for (int reg = 0; reg < 4; reg++)
                    sH[(s * 16 + quad * 4 + reg) * 136 + col] =
                        f2bf(acc[s][nt][reg] + rb2[nt]);
            }
        __syncthreads();
        // consume: node A then node B (contiguous CSR ranges)
        {
            int jb = max(begA, c0), je = min(endA, ce);
            for (int j = jb; j < je; j++) {
                int jl = j - c0;
                int src = sSrc[jl];
                u32x4 xv = *(const u32x4*)(xb + (long)src * H);
                short8 ev = *(const short8*)&sH[jl * 136 + fo];
                #pragma unroll
                for (int q = 0; q < 8; q++) {
                    float xf = bf2f((q & 1) ? (xv[q >> 1] >> 16) : (xv[q >> 1] & 0xffff));
                    float ef = bf2f((u32)(unsigned short)ev[q]);
                    a[q] += fmaxf(xf + ef, 0.0f);
                }
            }
            jb = max(endA, c0); je = min(endB, ce);
            for (int j = jb; j < je; j++) {
                int jl = j - c0;
                int src = sSrc[jl];
                u32x4 xv = *(const u32x4*)(xb + (long)src * H);
                short8 ev = *(const short8*)&sH[jl * 136 + fo];
                #pragma unroll
                for (int q = 0; q < 8; q++) {
                    float xf = bf2f((q & 1) ? (xv[q >> 1] >> 16) : (xv[q >> 1] & 0xffff));
                    float ef = bf2f((u32)(unsigned short)ev[q]);
                    b[q] += fmaxf(xf + ef, 0.0f);
                }
            }
        }
        __syncthreads();   // before next chunk overwrites sA/sSrc/sH
    }
    // self term + pack + store (one row per node)
    u32x4 xvA = *(const u32x4*)(xb + (long)nA * H);
    u32x4 oA;
    #pragma unroll
    for (int q = 0; q < 4; q++) {
        float o0 = bf2f(xvA[q] & 0xffff) + a[2 * q + 0];
        float o1 = bf2f(xvA[q] >> 16)    + a[2 * q + 1];
        oA[q] = (u32)f2bf(o0) | ((u32)f2bf(o1) << 16);
    }
    *(u32x4*)&xs_out[(long)nA * H + fo] = oA;
    u32x4 xvB = *(const u32x4*)(xb + (long)(nA + 1) * H);
    u32x4 oB;
    #pragma unroll
    for (int q = 0; q < 4; q++) {
        float o0 = bf2f(xvB[q] & 0xffff) + b[2 * q + 0];
        float o1 = bf2f(xvB[q] >> 16)    + b[2 * q + 1];
        oB[q] = (u32)f2bf(o0) | ((u32)f2bf(o1) << 16);
    }
    *(u32x4*)&xs_out[(long)(nA + 1) * H + fo] = oB;
}

// ---- conv MLP: 32-row tiles, single LDS buffer, high block count ----------
// 100000 = 3125 * 32 exactly -> no tail, no bounds checks.
__global__ __launch_bounds__(256) void conv_mlp_mfma(
    const u16* __restrict__ xs,
    const short8* __restrict__ pW1, const float* __restrict__ b1,
    const short8* __restrict__ pW2, const float* __restrict__ b2,
    u16* __restrict__ x_out)
{
    __shared__ u16 sA[32 * 136];
    int tid = threadIdx.x;
    int w = tid >> 6, lane = tid & 63, quad = lane >> 4, n15 = lane & 15;
    short8 fW1[4][2], fW2[4][2];
    #pragma unroll
    for (int kk = 0; kk < 4; kk++) {
        fW1[kk][0] = pW1[((w * 4 + kk) * 2 + 0) * 64 + lane];
        fW1[kk][1] = pW1[((w * 4 + kk) * 2 + 1) * 64 + lane];
        fW2[kk][0] = pW2[((w * 4 + kk) * 2 + 0) * 64 + lane];
        fW2[kk][1] = pW2[((w * 4 + kk) * 2 + 1) * 64 + lane];
    }
    float rb1[2] = { b1[w * 32 + n15], b1[w * 32 + 16 + n15] };
    float rb2[2] = { b2[w * 32 + n15], b2[w * 32 + 16 + n15] };
    const int ntile = N_NODES / 32;   // 3125 exact
    for (int tile = blockIdx.x; tile < ntile; tile += gridDim.x) {
        long row0 = (long)tile * 32;
        for (int idx = tid; idx < 32 * 16; idx += 256) {
            int r = idx >> 4, c8 = (idx & 15) << 3;
            *(uint4*)&sA[r * 136 + c8] = *(const uint4*)&xs[(row0 + r) * H + c8];
        }
        __syncthreads();
        // GEMM1
        f32x4 acc[2][2];
        #pragma unroll
        for (int s = 0; s < 2; s++) { acc[s][0] = (f32x4){0,0,0,0}; acc[s][1] = (f32x4){0,0,0,0}; }
        #pragma unroll
        for (int kk = 0; kk < 4; kk++) {
            #pragma unroll
            for (int s = 0; s < 2; s++) {
                short8 a = *(const short8*)&sA[(s * 16 + n15) * 136 + kk * 32 + quad * 8];
                acc[s][0] = __builtin_amdgcn_mfma_f32_16x16x32_bf16(a, fW1[kk][0], acc[s][0], 0, 0, 0);
                acc[s][1] = __builtin_amdgcn_mfma_f32_16x16x32_bf16(a, fW1[kk][1], acc[s][1], 0, 0, 0);
            }
        }
        __syncthreads();   // all sA reads done
        #pragma unroll
        for (int s = 0; s < 2; s++)
            #pragma unroll
            for (int nt = 0; nt < 2; nt++) {
                int col = w * 32 + nt * 16 + n15;
                #pragma unroll
                for (int reg = 0; reg < 4; reg++)
                    sA[(s * 16 + quad * 4 + reg) * 136 + col] =
                        f2bf(fmaxf(acc[s][nt][reg] + rb1[nt], 0.0f));
            }
        __syncthreads();
        // GEMM2
        #pragma unroll
        for (int s = 0; s < 2; s++) { acc[s][0] = (f32x4){0,0,0,0}; acc[s][1] = (f32x4){0,0,0,0}; }
        #pragma unroll
        for (int kk = 0; kk < 4; kk++) {
            #pragma unroll
            for (int s = 0; s < 2; s++) {
                short8 a = *(const short8*)&sA[(s * 16 + n15) * 136 + kk * 32 + quad * 8];
                acc[s][0] = __builtin_amdgcn_mfma_f32_16x16x32_bf16(a, fW2[kk][0], acc[s][0], 0, 0, 0);
                acc[s][1] = __builtin_amdgcn_mfma_f32_16x16x32_bf16(a, fW2[kk][1], acc[s][1], 0, 0, 0);
            }
        }
        __syncthreads();   // all sA reads done
        #pragma unroll
        for (int s = 0; s < 2; s++)
            #pragma unroll
            for (int nt = 0; nt < 2; nt++) {
                int col = w * 32 + nt * 16 + n15;
                #pragma unroll
                for (int reg = 0; reg < 4; reg++)
                    sA[(s * 16 + quad * 4 + reg) * 136 + col] =
                        f2bf(fmaxf(acc[s][nt][reg] + rb2[nt], 0.0f));
            }
        __syncthreads();
        for (int idx = tid; idx < 32 * 16; idx += 256) {
            int r = idx >> 4, c8 = (idx & 15) << 3;
            *(uint4*)&x_out[(row0 + r) * H + c8] = *(const uint4*)&sA[r * 136 + c8];
        }
        __syncthreads();
    }
}

// ---------------- mean-pool: vectorized, high-TLP, segment flush -----------
__global__ __launch_bounds__(256) void pool_kernel(
    const u16* __restrict__ x, const int* __restrict__ batch,
    float* __restrict__ sums, float* __restrict__ cnt)
{
    int sg   = threadIdx.x >> 6;
    int lane = threadIdx.x & 63;
    int fo = lane * 2;
    const int nper = (N_NODES + gridDim.x - 1) / gridDim.x;
    int n0 = blockIdx.x * nper;
    int n1 = min(n0 + nper, N_NODES);
    int cur = -1;
    float a0 = 0.0f, a1 = 0.0f, c = 0.0f;
    for (int n = n0 + sg; n < n1; n += 4) {
        int b = batch[n];
        if (b != cur) {
            if (cur >= 0) {
                atomicAdd(&sums[cur * H + fo],     a0);
                atomicAdd(&sums[cur * H + fo + 1], a1);
                if (lane == 0) atomicAdd(&cnt[cur], c);
            }
            a0 = a1 = 0.0f; c = 0.0f; cur = b;
        }
        u32 xv = *(const u32*)&x[(long)n * H + fo];
        a0 += bf2f(xv & 0xffff);
        a1 += bf2f(xv >> 16);
        c += 1.0f;
    }
    if (cur >= 0) {
        atomicAdd(&sums[cur * H + fo],     a0);
        atomicAdd(&sums[cur * H + fo + 1], a1);
        if (lane == 0) atomicAdd(&cnt[cur], c);
    }
}

// ---------------- regressor ------------------------------------------------
__global__ __launch_bounds__(128) void regressor_kernel(
    const float* __restrict__ sums, const float* __restrict__ cnt,
    const float* __restrict__ depth,
    const float* __restrict__ w1, const float* __restrict__ b1,
    const float* __restrict__ w2, const float* __restrict__ b2,
    float* __restrict__ out)
{
    __shared__ float s_mean[H];
    __shared__ float s_red[2];
    int b = blockIdx.x;
    int j = threadIdx.x;
    float c = fmaxf(cnt[b], 1.0f);
    s_mean[j] = sums[b * H + j] / c;
    __syncthreads();
    float h = b1[j];
    #pragma unroll 8
    for (int k = 0; k < H; k++) h += s_mean[k] * w1[k * H + j];
    h += depth[b] * w1[H * H + j];
    h = fmaxf(h, 0.0f);
    float p = h * w2[j];
    #pragma unroll
    for (int off = 32; off >= 1; off >>= 1) p += __shfl_down(p, off, 64);
    if ((j & 63) == 0) s_red[j >> 6] = p;
    __syncthreads();
    if (j == 0) out[b] = s_red[0] + s_red[1] + b2[0];
}

extern "C" void kernel_launch(void* const* d_in, const int* in_sizes, int n_in,
                              void* d_out, int out_size, void* d_ws, size_t ws_size,
                              hipStream_t stream)
{
    const int*   ids   = (const int*)  d_in[0];
    const int*   eidx  = (const int*)  d_in[1];
    const float* eattr = (const float*)d_in[2];
    const int*   batch = (const int*)  d_in[3];
    const float* depth = (const float*)d_in[4];
    const float* id_w1 = (const float*)d_in[5];
    const float* id_b1 = (const float*)d_in[6];
    const float* id_w2 = (const float*)d_in[7];
    const float* id_b2 = (const float*)d_in[8];
    const float* ed_w1 = (const float*)d_in[9];
    const float* ed_b1 = (const float*)d_in[10];
    const float* ed_w2 = (const float*)d_in[11];
    const float* ed_b2 = (const float*)d_in[12];
    const float* c1_w1 = (const float*)d_in[13];
    const float* c1_b1 = (const float*)d_in[14];
    const float* c1_w2 = (const float*)d_in[15];
    const float* c1_b2 = (const float*)d_in[16];
    const float* c2_w1 = (const float*)d_in[17];
    const float* c2_b1 = (const float*)d_in[18];
    const float* c2_w2 = (const float*)d_in[19];
    const float* c2_b2 = (const float*)d_in[20];
    const float* rg_w1 = (const float*)d_in[21];
    const float* rg_b1 = (const float*)d_in[22];
    const float* rg_w2 = (const float*)d_in[23];
    const float* rg_b2 = (const float*)d_in[24];

    char* ws = (char*)d_ws;
    u16*   attr_perm = (u16*) (ws);                     //   9,600,000 B (bf16, CSR order)
    u16*   x_buf    = (u16*)  (ws + 9600000);           //  25,600,000 B
    u16*   xs_buf   = (u16*)  (ws + 35200000);          //  25,600,000 B
    float* sums_buf = (float*)(ws + 60800000);          //     262,144 B
    float* cnt_buf  = (float*)(ws + 61062144);          //       2,048 B
    int*   counts   = (int*)  (ws + 61064192);          //     401,408 B
    int*   chunk_sc = (int*)  (ws + 61465600);          //     401,408 B
    int*   bsum_raw = (int*)  (ws + 61867008);          //         512 B
    int*   bsum_sc  = (int*)  (ws + 61867520);          //         512 B
    int*   src_list = (int*)  (ws + 61868032);          //   2,400,000 B
    short8* ed_w1p  = (short8*)(ws + 64268032);         //       8,192 B
    short8* ed_w2p  = (short8*)(ws + 64276224);         //      32,768 B
    short8* c1_w1p  = (short8*)(ws + 64308992);
    short8* c1_w2p  = (short8*)(ws + 64341760);
    short8* c2_w1p  = (short8*)(ws + 64374528);
    short8* c2_w2p  = (short8*)(ws + 64407296);
    short8* id_w2p  = (short8*)(ws + 64440064);
    int*   row_start = counts;   // counts is dead after fill_kernel; reuse

    pack_all_kernel<<<50, 256, 0, stream>>>(
        ed_w1, ed_w2, c1_w1, c1_w2, c2_w1, c2_w2, id_w2,
        ed_w1p, ed_w2p, c1_w1p, c1_w2p, c2_w1p, c2_w2p, id_w2p);

    // CSR build (fill also permutes attr to bf16 CSR order)
    hipMemsetAsync(counts, 0, 401408, stream);
    hist_kernel <<<(N_EDGES + 255) / 256, 256, 0, stream>>>(eidx, counts);
    scan1_kernel<<<N_CHUNKS, SCAN_CHUNK, 0, stream>>>(counts, chunk_sc, bsum_raw);
    scan2_kernel<<<1, 128, 0, stream>>>(bsum_raw, bsum_sc);
    fill_kernel <<<(N_EDGES + 255) / 256, 256, 0, stream>>>(eidx, chunk_sc, bsum_sc,
                                                            counts, src_list,
                                                            eattr, attr_perm);
    finalize_offsets<<<(N_NODES + 256) / 256, 256, 0, stream>>>(chunk_sc, bsum_sc, row_start);

    // front-end (edge_mlp is gone: e recomputed inside gine_msg_fused)
    node_mlp_mfma<<<768, 256, 0, stream>>>(ids, id_w1, id_b1, id_w2p, id_b2, x_buf);

    // conv 1
    gine_msg_fused<<<3125, 256, 0, stream>>>(row_start, src_list, attr_perm, x_buf,
                                             ed_w1p, ed_b1, ed_w2p, ed_b2, xs_buf);
    conv_mlp_mfma<<<3125, 256, 0, stream>>>(xs_buf, c1_w1p, c1_b1, c1_w2p, c1_b2, x_buf);

    // conv 2
    gine_msg_fused<<<3125, 256, 0, stream>>>(row_start, src_list, attr_perm, x_buf,
                                             ed_w1p, ed_b1, ed_w2p, ed_b2, xs_buf);
    conv_mlp_mfma<<<3125, 256, 0, stream>>>(xs_buf, c2_w1p, c2_b1, c2_w2p, c2_b2, x_buf);

    // pooling + regressor
    hipMemsetAsync(sums_buf, 0, (size_t)(NB * H + NB) * 4, stream);
    pool_kernel<<<2048, 256, 0, stream>>>(x_buf, batch, sums_buf, cnt_buf);
    regressor_kernel<<<NB, 128, 0, stream>>>(sums_buf, cnt_buf, depth,
                                             rg_w1, rg_b1, rg_w2, rg_b2, (float*)d_out);
}

// Round 6
// 425.826 us; speedup vs baseline: 1.3327x; 1.3327x over previous
//
#include <hip/hip_runtime.h>
#include <hip/hip_bf16.h>

#define N_NODES 100000
#define N_EDGES 600000
#define NB      512
#define H       128
#define ED      8
#define SCAN_CHUNK 1024
#define N_CHUNKS   98   // 98*1024 = 100352 >= N_NODES+1

typedef __attribute__((ext_vector_type(8))) short short8;
typedef __attribute__((ext_vector_type(4))) float f32x4;
typedef __attribute__((ext_vector_type(4))) unsigned int u32x4;
typedef unsigned short u16;
typedef unsigned int   u32;

static __device__ __forceinline__ u16 f2bf(float f) {
    u32 u = __float_as_uint(f);
    u32 r = u + 0x7fffu + ((u >> 16) & 1u);
    return (u16)(r >> 16);
}
static __device__ __forceinline__ float bf2f(u32 h) {
    return __uint_as_float(h << 16);
}
// packed f32->bf16 (RNE, same as f2bf): lo->bits[15:0], hi->bits[31:16]
static __device__ __forceinline__ u32 bfpack(float lo, float hi) {
    u32 r;
    asm("v_cvt_pk_bf16_f32 %0, %1, %2" : "=v"(r) : "v"(lo), "v"(hi));
    return r;
}

// ---- weight pack (ALL matrices in one launch) -----------------------------
__global__ __launch_bounds__(256) void pack_all_kernel(
    const float* __restrict__ W0, const float* __restrict__ W1,
    const float* __restrict__ W2, const float* __restrict__ W3,
    const float* __restrict__ W4, const float* __restrict__ W5,
    const float* __restrict__ W6,
    short8* __restrict__ O0, short8* __restrict__ O1,
    short8* __restrict__ O2, short8* __restrict__ O3,
    short8* __restrict__ O4, short8* __restrict__ O5,
    short8* __restrict__ O6)
{
    int gid = blockIdx.x * 256 + threadIdx.x;
    const int total = 512 + 6 * 2048;
    if (gid >= total) return;
    const float* W; short8* O; int Krows, kkmax, slot;
    if (gid < 512) { W = W0; O = O0; Krows = ED; kkmax = 1; slot = gid; }
    else {
        int m = (gid - 512) / 2048;
        slot = (gid - 512) % 2048;
        Krows = H; kkmax = 4;
        switch (m) {
            case 0: W = W1; O = O1; break;
            case 1: W = W2; O = O2; break;
            case 2: W = W3; O = O3; break;
            case 3: W = W4; O = O4; break;
            case 4: W = W5; O = O5; break;
            default: W = W6; O = O6; break;
        }
    }
    int lane = slot & 63;
    int t = slot >> 6;
    int nt = t & 1; t >>= 1;
    int kk = t % kkmax;
    int w  = t / kkmax;
    int quad = lane >> 4, n15 = lane & 15;
    int n = w * 32 + nt * 16 + n15;
    short8 v;
    #pragma unroll
    for (int j = 0; j < 8; j++) {
        int k = kk * 32 + quad * 8 + j;
        v[j] = (k < Krows) ? (short)f2bf(W[k * H + n]) : (short)0;
    }
    O[slot] = v;
}

// ---------------- CSR build ------------------------------------------------
__global__ __launch_bounds__(256) void hist_kernel(
    const int* __restrict__ edge_index, int* __restrict__ counts)
{
    int e = blockIdx.x * 256 + threadIdx.x;
    if (e < N_EDGES) atomicAdd(&counts[edge_index[N_EDGES + e]], 1);
}

__global__ __launch_bounds__(SCAN_CHUNK) void scan1_kernel(
    const int* __restrict__ counts, int* __restrict__ chunk_scan,
    int* __restrict__ bsum_raw)
{
    __shared__ int s[SCAN_CHUNK];
    int tid = threadIdx.x;
    int gid = blockIdx.x * SCAN_CHUNK + tid;
    int v = counts[gid];
    s[tid] = v;
    __syncthreads();
    #pragma unroll
    for (int off = 1; off < SCAN_CHUNK; off <<= 1) {
        int t = (tid >= off) ? s[tid - off] : 0;
        __syncthreads();
        s[tid] += t;
        __syncthreads();
    }
    chunk_scan[gid] = s[tid] - v;
    if (tid == SCAN_CHUNK - 1) bsum_raw[blockIdx.x] = s[tid];
}

__global__ __launch_bounds__(128) void scan2_kernel(
    const int* __restrict__ bsum_raw, int* __restrict__ bsum_scan)
{
    __shared__ int s[128];
    int tid = threadIdx.x;
    int v = (tid < N_CHUNKS) ? bsum_raw[tid] : 0;
    s[tid] = v;
    __syncthreads();
    #pragma unroll
    for (int off = 1; off < 128; off <<= 1) {
        int t = (tid >= off) ? s[tid - off] : 0;
        __syncthreads();
        s[tid] += t;
        __syncthreads();
    }
    bsum_scan[tid] = s[tid] - v;
}

// fill: src_list[pos]=src (CSR order); attr_perm[pos]=bf16(attr[e]) (CSR order)
__global__ __launch_bounds__(256) void fill_kernel(
    const int* __restrict__ edge_index,
    const int* __restrict__ chunk_scan, const int* __restrict__ bsum_scan,
    int* __restrict__ counts, int* __restrict__ src_list,
    const float* __restrict__ attr, u16* __restrict__ attr_perm)
{
    int e = blockIdx.x * 256 + threadIdx.x;
    if (e >= N_EDGES) return;
    int src = edge_index[e];
    int dst = edge_index[N_EDGES + e];
    int slot = atomicAdd(&counts[dst], -1) - 1;
    int pos = chunk_scan[dst] + bsum_scan[dst >> 10] + slot;
    src_list[pos] = src;
    float4 v0 = *(const float4*)&attr[(long)e * ED];
    float4 v1 = *(const float4*)&attr[(long)e * ED + 4];
    u32 w0 = bfpack(v0.x, v0.y);
    u32 w1 = bfpack(v0.z, v0.w);
    u32 w2 = bfpack(v1.x, v1.y);
    u32 w3 = bfpack(v1.z, v1.w);
    *(uint4*)&attr_perm[(long)pos * ED] = make_uint4(w0, w1, w2, w3);
}

// row_start[n] = chunk_scan[n] + bsum_scan[n>>10]   (n in [0, N])
__global__ __launch_bounds__(256) void finalize_offsets(
    const int* __restrict__ chunk_scan, const int* __restrict__ bsum_scan,
    int* __restrict__ row_start)
{
    int i = blockIdx.x * 256 + threadIdx.x;
    if (i <= N_NODES) row_start[i] = chunk_scan[i] + bsum_scan[i >> 10];
}

// ---------------- node MLP (MFMA layer2): x bf16 [N,H] ---------------------
__global__ __launch_bounds__(256) void node_mlp_mfma(
    const int* __restrict__ ids,
    const float* __restrict__ w1, const float* __restrict__ b1,
    const short8* __restrict__ pW2, const float* __restrict__ b2,
    u16* __restrict__ x_out)
{
    __shared__ u16 sH[64 * 136];
    __shared__ float s_x0[64];
    int tid = threadIdx.x;
    int w = tid >> 6, lane = tid & 63, quad = lane >> 4, n15 = lane & 15;
    short8 fW2[4][2];
    #pragma unroll
    for (int kk = 0; kk < 4; kk++) {
        fW2[kk][0] = pW2[((w * 4 + kk) * 2 + 0) * 64 + lane];
        fW2[kk][1] = pW2[((w * 4 + kk) * 2 + 1) * 64 + lane];
    }
    float rb2[2] = { b2[w * 32 + n15], b2[w * 32 + 16 + n15] };
    float w1c = w1[tid & 127], b1c = b1[tid & 127];
    const int ntile = (N_NODES + 63) / 64;
    for (int tile = blockIdx.x; tile < ntile; tile += gridDim.x) {
        int row0 = tile * 64;
        if (tid < 64) {
            int n = row0 + tid;
            float x0 = (n < N_NODES) ? (float)ids[n] / 281474976710655.0f : 0.0f;
            s_x0[tid] = fminf(fmaxf(x0, 0.0f), 1.0f);
        }
        __syncthreads();
        int half = tid >> 7, c = tid & 127;
        #pragma unroll
        for (int rr = 0; rr < 32; rr += 2) {
            int r = half + rr * 2;
            u32 p = bfpack(fmaxf(s_x0[r] * w1c + b1c, 0.0f),
                           fmaxf(s_x0[r + 2] * w1c + b1c, 0.0f));
            sH[r * 136 + c]       = (u16)p;
            sH[(r + 2) * 136 + c] = (u16)(p >> 16);
        }
        __syncthreads();
        f32x4 acc[4][2];
        #pragma unroll
        for (int s = 0; s < 4; s++) { acc[s][0] = (f32x4){0,0,0,0}; acc[s][1] = (f32x4){0,0,0,0}; }
        #pragma unroll
        for (int kk = 0; kk < 4; kk++) {
            #pragma unroll
            for (int s = 0; s < 4; s++) {
                short8 a = *(const short8*)&sH[(s * 16 + n15) * 136 + kk * 32 + quad * 8];
                acc[s][0] = __builtin_amdgcn_mfma_f32_16x16x32_bf16(a, fW2[kk][0], acc[s][0], 0, 0, 0);
                acc[s][1] = __builtin_amdgcn_mfma_f32_16x16x32_bf16(a, fW2[kk][1], acc[s][1], 0, 0, 0);
            }
        }
        __syncthreads();
        #pragma unroll
        for (int s = 0; s < 4; s++)
            #pragma unroll
            for (int nt = 0; nt < 2; nt++) {
                int col = w * 32 + nt * 16 + n15;
                int rb = (s * 16 + quad * 4) * 136 + col;
                u32 p0 = bfpack(acc[s][nt][0] + rb2[nt], acc[s][nt][1] + rb2[nt]);
                u32 p1 = bfpack(acc[s][nt][2] + rb2[nt], acc[s][nt][3] + rb2[nt]);
                sH[rb]       = (u16)p0;
                sH[rb + 136] = (u16)(p0 >> 16);
                sH[rb + 272] = (u16)p1;
                sH[rb + 408] = (u16)(p1 >> 16);
            }
        __syncthreads();
        for (int idx = tid; idx < 64 * 16; idx += 256) {
            int r = idx >> 4, c8 = (idx & 15) << 3;
            int n = row0 + r;
            if (n < N_NODES)
                *(uint4*)&x_out[(long)n * H + c8] = *(const uint4*)&sH[r * 136 + c8];
        }
        __syncthreads();
    }
}

// ---- edge MLP v3: linear stream (CSR-ordered attr in, linear e out) -------
// A-fragments load straight from global (K=32 with cols 8..31 == 0, so only
// quad-0 lanes carry data). No sA, no pos scatter. LDS = sH only (17.4 KB).
__global__ __launch_bounds__(256) void edge_mlp_mfma(
    const u16* __restrict__ attr_perm,
    const short8* __restrict__ pW1, const float* __restrict__ b1,
    const short8* __restrict__ pW2, const float* __restrict__ b2,
    u16* __restrict__ e_perm)
{
    __shared__ u16 sH[64 * 136];
    int tid = threadIdx.x;
    int w = tid >> 6, lane = tid & 63, quad = lane >> 4, n15 = lane & 15;
    short8 fW1[2];
    fW1[0] = pW1[(w * 2 + 0) * 64 + lane];
    fW1[1] = pW1[(w * 2 + 1) * 64 + lane];
    short8 fW2[4][2];
    #pragma unroll
    for (int kk = 0; kk < 4; kk++) {
        fW2[kk][0] = pW2[((w * 4 + kk) * 2 + 0) * 64 + lane];
        fW2[kk][1] = pW2[((w * 4 + kk) * 2 + 1) * 64 + lane];
    }
    float rb1[2] = { b1[w * 32 + n15], b1[w * 32 + 16 + n15] };
    float rb2[2] = { b2[w * 32 + n15], b2[w * 32 + 16 + n15] };
    const short8 zero8 = (short8){0,0,0,0,0,0,0,0};
    const int ntile = N_EDGES / 64;   // 9375 exact
    for (int tile = blockIdx.x; tile < ntile; tile += gridDim.x) {
        int row0 = tile * 64;
        // A-fragments: quad 0 holds attr cols 0..7; quads 1..3 are zero pad
        short8 av[4];
        #pragma unroll
        for (int s = 0; s < 4; s++) {
            av[s] = zero8;
            if (quad == 0)
                av[s] = *(const short8*)&attr_perm[(long)(row0 + s * 16 + n15) * ED];
        }
        // GEMM1 (K=32, one step)
        f32x4 acc[4][2];
        #pragma unroll
        for (int s = 0; s < 4; s++) { acc[s][0] = (f32x4){0,0,0,0}; acc[s][1] = (f32x4){0,0,0,0}; }
        #pragma unroll
        for (int s = 0; s < 4; s++) {
            acc[s][0] = __builtin_amdgcn_mfma_f32_16x16x32_bf16(av[s], fW1[0], acc[s][0], 0, 0, 0);
            acc[s][1] = __builtin_amdgcn_mfma_f32_16x16x32_bf16(av[s], fW1[1], acc[s][1], 0, 0, 0);
        }
        #pragma unroll
        for (int s = 0; s < 4; s++)
            #pragma unroll
            for (int nt = 0; nt < 2; nt++) {
                int col = w * 32 + nt * 16 + n15;
                int rb = (s * 16 + quad * 4) * 136 + col;
                u32 p0 = bfpack(fmaxf(acc[s][nt][0] + rb1[nt], 0.0f),
                                fmaxf(acc[s][nt][1] + rb1[nt], 0.0f));
                u32 p1 = bfpack(fmaxf(acc[s][nt][2] + rb1[nt], 0.0f),
                                fmaxf(acc[s][nt][3] + rb1[nt], 0.0f));
                sH[rb]       = (u16)p0;
                sH[rb + 136] = (u16)(p0 >> 16);
                sH[rb + 272] = (u16)p1;
                sH[rb + 408] = (u16)(p1 >> 16);
            }
        __syncthreads();
        // GEMM2 (K=128)
        #pragma unroll
        for (int s = 0; s < 4; s++) { acc[s][0] = (f32x4){0,0,0,0}; acc[s][1] = (f32x4){0,0,0,0}; }
        #pragma unroll
        for (int kk = 0; kk < 4; kk++) {
            #pragma unroll
            for (int s = 0; s < 4; s++) {
                short8 a = *(const short8*)&sH[(s * 16 + n15) * 136 + kk * 32 + quad * 8];
                acc[s][0] = __builtin_amdgcn_mfma_f32_16x16x32_bf16(a, fW2[kk][0], acc[s][0], 0, 0, 0);
                acc[s][1] = __builtin_amdgcn_mfma_f32_16x16x32_bf16(a, fW2[kk][1], acc[s][1], 0, 0, 0);
            }
        }
        __syncthreads();
        #pragma unroll
        for (int s = 0; s < 4; s++)
            #pragma unroll
            for (int nt = 0; nt < 2; nt++) {
                int col = w * 32 + nt * 16 + n15;
                int rb = (s * 16 + quad * 4) * 136 + col;
                u32 p0 = bfpack(acc[s][nt][0] + rb2[nt], acc[s][nt][1] + rb2[nt]);
                u32 p1 = bfpack(acc[s][nt][2] + rb2[nt], acc[s][nt][3] + rb2[nt]);
                sH[rb]       = (u16)p0;
                sH[rb + 136] = (u16)(p0 >> 16);
                sH[rb + 272] = (u16)p1;
                sH[rb + 408] = (u16)(p1 >> 16);
            }
        __syncthreads();
        // linear coalesced store
        for (int idx = tid; idx < 64 * 16; idx += 256) {
            int r = idx >> 4, c8 = (idx & 15) << 3;
            *(uint4*)&e_perm[(long)(row0 + r) * H + c8] = *(const uint4*)&sH[r * 136 + c8];
        }
        __syncthreads();
    }
}

// ---- aggregate v5: 16-lane group handles 2 nodes, dual interleaved chains -
// per group: 2 nodes x 2-unroll x 2 loads = 8 loads in flight (2x round 3).
static __device__ __forceinline__ void acc8(float* a, u32x4 xv, u32x4 ev) {
    #pragma unroll
    for (int q = 0; q < 4; q++) {
        a[2 * q + 0] += fmaxf(bf2f(xv[q] & 0xffff) + bf2f(ev[q] & 0xffff), 0.0f);
        a[2 * q + 1] += fmaxf(bf2f(xv[q] >> 16)    + bf2f(ev[q] >> 16),    0.0f);
    }
}

__global__ __launch_bounds__(256) void aggregate_kernel(
    const int* __restrict__ row_start,
    const int* __restrict__ src_list,
    const u16* __restrict__ e_perm,
    const u16* __restrict__ x,
    u16* __restrict__ xs_out)
{
    int tid  = threadIdx.x;
    int lane = tid & 63;
    int l16  = lane & 15;
    int base = lane & 48;
    int fo   = l16 * 8;
    int g    = tid >> 4;                  // 16 groups per block
    int nA   = blockIdx.x * 32 + g * 2;   // 3125 * 32 = 100000 exact
    const u16* xb = x + fo;

    int rsA = row_start[nA];
    int rsB = row_start[nA + 1];
    int rsC = row_start[nA + 2];
    float a0[8], a1[8], b0[8], b1[8];
    #pragma unroll
    for (int q = 0; q < 8; q++) { a0[q] = 0.0f; a1[q] = 0.0f; b0[q] = 0.0f; b1[q] = 0.0f; }

    int jA = rsA, endA = rsB;
    int jB = rsB, endB = rsC;
    while (jA < endA || jB < endB) {
        int mA = endA - jA; mA = mA > 16 ? 16 : (mA < 0 ? 0 : mA);
        int mB = endB - jB; mB = mB > 16 ? 16 : (mB < 0 ? 0 : mB);
        int svA = mA ? src_list[jA + min(l16, mA - 1)] : 0;
        int svB = mB ? src_list[jB + min(l16, mB - 1)] : 0;
        const u16* eA = e_perm + (long)jA * H + fo;
        const u16* eB = e_perm + (long)jB * H + fo;
        int mD = mA < mB ? mA : mB;
        int i = 0;
        for (; i + 2 <= mD; i += 2) {   // dual-node x 2-unroll: 8 loads in flight
            int sa0 = __shfl(svA, base | i);
            int sa1 = __shfl(svA, base | (i + 1));
            int sb0 = __shfl(svB, base | i);
            int sb1 = __shfl(svB, base | (i + 1));
            u32x4 va0 = *(const u32x4*)(xb + (long)sa0 * H);
            u32x4 wa0 = *(const u32x4*)(eA + (long)(i + 0) * H);
            u32x4 vb0 = *(const u32x4*)(xb + (long)sb0 * H);
            u32x4 wb0 = *(const u32x4*)(eB + (long)(i + 0) * H);
            u32x4 va1 = *(const u32x4*)(xb + (long)sa1 * H);
            u32x4 wa1 = *(const u32x4*)(eA + (long)(i + 1) * H);
            u32x4 vb1 = *(const u32x4*)(xb + (long)sb1 * H);
            u32x4 wb1 = *(const u32x4*)(eB + (long)(i + 1) * H);
            acc8(a0, va0, wa0);
            acc8(b0, vb0, wb0);
            acc8(a1, va1, wa1);
            acc8(b1, vb1, wb1);
        }
        if (i < mD) {   // one paired leftover
            int sa0 = __shfl(svA, base | i);
            int sb0 = __shfl(svB, base | i);
            u32x4 va0 = *(const u32x4*)(xb + (long)sa0 * H);
            u32x4 wa0 = *(const u32x4*)(eA + (long)i * H);
            u32x4 vb0 = *(const u32x4*)(xb + (long)sb0 * H);
            u32x4 wb0 = *(const u32x4*)(eB + (long)i * H);
            acc8(a0, va0, wa0);
            acc8(b0, vb0, wb0);
            i++;
        }
        int k = i;
        for (; k + 2 <= mA; k += 2) {   // A-only tail
            int sa0 = __shfl(svA, base | k);
            int sa1 = __shfl(svA, base | (k + 1));
            u32x4 va0 = *(const u32x4*)(xb + (long)sa0 * H);
            u32x4 wa0 = *(const u32x4*)(eA + (long)(k + 0) * H);
            u32x4 va1 = *(const u32x4*)(xb + (long)sa1 * H);
            u32x4 wa1 = *(const u32x4*)(eA + (long)(k + 1) * H);
            acc8(a0, va0, wa0);
            acc8(a1, va1, wa1);
        }
        if (k < mA) {
            int sa0 = __shfl(svA, base | k);
            u32x4 va0 = *(const u32x4*)(xb + (long)sa0 * H);
            u32x4 wa0 = *(const u32x4*)(eA + (long)k * H);
            acc8(a0, va0, wa0);
        }
        k = i;
        for (; k + 2 <= mB; k += 2) {   // B-only tail
            int sb0 = __shfl(svB, base | k);
            int sb1 = __shfl(svB, base | (k + 1));
            u32x4 vb0 = *(const u32x4*)(xb + (long)sb0 * H);
            u32x4 wb0 = *(const u32x4*)(eB + (long)(k + 0) * H);
            u32x4 vb1 = *(const u32x4*)(xb + (long)sb1 * H);
            u32x4 wb1 = *(const u32x4*)(eB + (long)(k + 1) * H);
            acc8(b0, vb0, wb0);
            acc8(b1, vb1, wb1);
        }
        if (k < mB) {
            int sb0 = __shfl(svB, base | k);
            u32x4 vb0 = *(const u32x4*)(xb + (long)sb0 * H);
            u32x4 wb0 = *(const u32x4*)(eB + (long)k * H);
            acc8(b0, vb0, wb0);
        }
        jA += mA; jB += mB;
    }
    // self + combine + pack + store (node A then node B)
    u32x4 xvA = *(const u32x4*)(xb + (long)nA * H);
    u32x4 oA;
    #pragma unroll
    for (int q = 0; q < 4; q++) {
        float o0 = bf2f(xvA[q] & 0xffff) + (a0[2 * q + 0] + a1[2 * q + 0]);
        float o1 = bf2f(xvA[q] >> 16)    + (a0[2 * q + 1] + a1[2 * q + 1]);
        oA[q] = bfpack(o0, o1);
    }
    *(u32x4*)&xs_out[(long)nA * H + fo] = oA;
    u32x4 xvB = *(const u32x4*)(xb + (long)(nA + 1) * H);
    u32x4 oB;
    #pragma unroll
    for (int q = 0; q < 4; q++) {
        float o0 = bf2f(xvB[q] & 0xffff) + (b0[2 * q + 0] + b1[2 * q + 0]);
        float o1 = bf2f(xvB[q] >> 16)    + (b0[2 * q + 1] + b1[2 * q + 1]);
        oB[q] = bfpack(o0, o1);
    }
    *(u32x4*)&xs_out[(long)(nA + 1) * H + fo] = oB;
}

// ---- conv MLP: 32-row tiles, single LDS buffer, high block count ----------
__global__ __launch_bounds__(256) void conv_mlp_mfma(
    const u16* __restrict__ xs,
    const short8* __restrict__ pW1, const float* __restrict__ b1,
    const short8* __restrict__ pW2, const float* __restrict__ b2,
    u16* __restrict__ x_out)
{
    __shared__ u16 sA[32 * 136];
    int tid = threadIdx.x;
    int w = tid >> 6, lane = tid & 63, quad = lane >> 4, n15 = lane & 15;
    short8 fW1[4][2], fW2[4][2];
    #pragma unroll
    for (int kk = 0; kk < 4; kk++) {
        fW1[kk][0] = pW1[((w * 4 + kk) * 2 + 0) * 64 + lane];
        fW1[kk][1] = pW1[((w * 4 + kk) * 2 + 1) * 64 + lane];
        fW2[kk][0] = pW2[((w * 4 + kk) * 2 + 0) * 64 + lane];
        fW2[kk][1] = pW2[((w * 4 + kk) * 2 + 1) * 64 + lane];
    }
    float rb1[2] = { b1[w * 32 + n15], b1[w * 32 + 16 + n15] };
    float rb2[2] = { b2[w * 32 + n15], b2[w * 32 + 16 + n15] };
    const int ntile = N_NODES / 32;   // 3125 exact
    for (int tile = blockIdx.x; tile < ntile; tile += gridDim.x) {
        long row0 = (long)tile * 32;
        for (int idx = tid; idx < 32 * 16; idx += 256) {
            int r = idx >> 4, c8 = (idx & 15) << 3;
            *(uint4*)&sA[r * 136 + c8] = *(const uint4*)&xs[(row0 + r) * H + c8];
        }
        __syncthreads();
        // GEMM1
        f32x4 acc[2][2];
        #pragma unroll
        for (int s = 0; s < 2; s++) { acc[s][0] = (f32x4){0,0,0,0}; acc[s][1] = (f32x4){0,0,0,0}; }
        #pragma unroll
        for (int kk = 0; kk < 4; kk++) {
            #pragma unroll
            for (int s = 0; s < 2; s++) {
                short8 a = *(const short8*)&sA[(s * 16 + n15) * 136 + kk * 32 + quad * 8];
                acc[s][0] = __builtin_amdgcn_mfma_f32_16x16x32_bf16(a, fW1[kk][0], acc[s][0], 0, 0, 0);
                acc[s][1] = __builtin_amdgcn_mfma_f32_16x16x32_bf16(a, fW1[kk][1], acc[s][1], 0, 0, 0);
            }
        }
        __syncthreads();   // all sA reads done
        #pragma unroll
        for (int s = 0; s < 2; s++)
            #pragma unroll
            for (int nt = 0; nt < 2; nt++) {
                int col = w * 32 + nt * 16 + n15;
                int rb = (s * 16 + quad * 4) * 136 + col;
                u32 p0 = bfpack(fmaxf(acc[s][nt][0] + rb1[nt], 0.0f),
                                fmaxf(acc[s][nt][1] + rb1[nt], 0.0f));
                u32 p1 = bfpack(fmaxf(acc[s][nt][2] + rb1[nt], 0.0f),
                                fmaxf(acc[s][nt][3] + rb1[nt], 0.0f));
                sA[rb]       = (u16)p0;
                sA[rb + 136] = (u16)(p0 >> 16);
                sA[rb + 272] = (u16)p1;
                sA[rb + 408] = (u16)(p1 >> 16);
            }
        __syncthreads();
        // GEMM2
        #pragma unroll
        for (int s = 0; s < 2; s++) { acc[s][0] = (f32x4){0,0,0,0}; acc[s][1] = (f32x4){0,0,0,0}; }
        #pragma unroll
        for (int kk = 0; kk < 4; kk++) {
            #pragma unroll
            for (int s = 0; s < 2; s++) {
                short8 a = *(const short8*)&sA[(s * 16 + n15) * 136 + kk * 32 + quad * 8];
                acc[s][0] = __builtin_amdgcn_mfma_f32_16x16x32_bf16(a, fW2[kk][0], acc[s][0], 0, 0, 0);
                acc[s][1] = __builtin_amdgcn_mfma_f32_16x16x32_bf16(a, fW2[kk][1], acc[s][1], 0, 0, 0);
            }
        }
        __syncthreads();   // all sA reads done
        #pragma unroll
        for (int s = 0; s < 2; s++)
            #pragma unroll
            for (int nt = 0; nt < 2; nt++) {
                int col = w * 32 + nt * 16 + n15;
                int rb = (s * 16 + quad * 4) * 136 + col;
                u32 p0 = bfpack(fmaxf(acc[s][nt][0] + rb2[nt], 0.0f),
                                fmaxf(acc[s][nt][1] + rb2[nt], 0.0f));
                u32 p1 = bfpack(fmaxf(acc[s][nt][2] + rb2[nt], 0.0f),
                                fmaxf(acc[s][nt][3] + rb2[nt], 0.0f));
                sA[rb]       = (u16)p0;
                sA[rb + 136] = (u16)(p0 >> 16);
                sA[rb + 272] = (u16)p1;
                sA[rb + 408] = (u16)(p1 >> 16);
            }
        __syncthreads();
        for (int idx = tid; idx < 32 * 16; idx += 256) {
            int r = idx >> 4, c8 = (idx & 15) << 3;
            *(uint4*)&x_out[(row0 + r) * H + c8] = *(const uint4*)&sA[r * 136 + c8];
        }
        __syncthreads();
    }
}

// ---------------- mean-pool: vectorized, high-TLP, segment flush -----------
__global__ __launch_bounds__(256) void pool_kernel(
    const u16* __restrict__ x, const int* __restrict__ batch,
    float* __restrict__ sums, float* __restrict__ cnt)
{
    int sg   = threadIdx.x >> 6;
    int lane = threadIdx.x & 63;
    int fo = lane * 2;
    const int nper = (N_NODES + gridDim.x - 1) / gridDim.x;
    int n0 = blockIdx.x * nper;
    int n1 = min(n0 + nper, N_NODES);
    int cur = -1;
    float a0 = 0.0f, a1 = 0.0f, c = 0.0f;
    for (int n = n0 + sg; n < n1; n += 4) {
        int b = batch[n];
        if (b != cur) {
            if (cur >= 0) {
                atomicAdd(&sums[cur * H + fo],     a0);
                atomicAdd(&sums[cur * H + fo + 1], a1);
                if (lane == 0) atomicAdd(&cnt[cur], c);
            }
            a0 = a1 = 0.0f; c = 0.0f; cur = b;
        }
        u32 xv = *(const u32*)&x[(long)n * H + fo];
        a0 += bf2f(xv & 0xffff);
        a1 += bf2f(xv >> 16);
        c += 1.0f;
    }
    if (cur >= 0) {
        atomicAdd(&sums[cur * H + fo],     a0);
        atomicAdd(&sums[cur * H + fo + 1], a1);
        if (lane == 0) atomicAdd(&cnt[cur], c);
    }
}

// ---------------- regressor ------------------------------------------------
__global__ __launch_bounds__(128) void regressor_kernel(
    const float* __restrict__ sums, const float* __restrict__ cnt,
    const float* __restrict__ depth,
    const float* __restrict__ w1, const float* __restrict__ b1,
    const float* __restrict__ w2, const float* __restrict__ b2,
    float* __restrict__ out)
{
    __shared__ float s_mean[H];
    __shared__ float s_red[2];
    int b = blockIdx.x;
    int j = threadIdx.x;
    float c = fmaxf(cnt[b], 1.0f);
    s_mean[j] = sums[b * H + j] / c;
    __syncthreads();
    float h = b1[j];
    #pragma unroll 8
    for (int k = 0; k < H; k++) h += s_mean[k] * w1[k * H + j];
    h += depth[b] * w1[H * H + j];
    h = fmaxf(h, 0.0f);
    float p = h * w2[j];
    #pragma unroll
    for (int off = 32; off >= 1; off >>= 1) p += __shfl_down(p, off, 64);
    if ((j & 63) == 0) s_red[j >> 6] = p;
    __syncthreads();
    if (j == 0) out[b] = s_red[0] + s_red[1] + b2[0];
}

extern "C" void kernel_launch(void* const* d_in, const int* in_sizes, int n_in,
                              void* d_out, int out_size, void* d_ws, size_t ws_size,
                              hipStream_t stream)
{
    const int*   ids   = (const int*)  d_in[0];
    const int*   eidx  = (const int*)  d_in[1];
    const float* eattr = (const float*)d_in[2];
    const int*   batch = (const int*)  d_in[3];
    const float* depth = (const float*)d_in[4];
    const float* id_w1 = (const float*)d_in[5];
    const float* id_b1 = (const float*)d_in[6];
    const float* id_w2 = (const float*)d_in[7];
    const float* id_b2 = (const float*)d_in[8];
    const float* ed_w1 = (const float*)d_in[9];
    const float* ed_b1 = (const float*)d_in[10];
    const float* ed_w2 = (const float*)d_in[11];
    const float* ed_b2 = (const float*)d_in[12];
    const float* c1_w1 = (const float*)d_in[13];
    const float* c1_b1 = (const float*)d_in[14];
    const float* c1_w2 = (const float*)d_in[15];
    const float* c1_b2 = (const float*)d_in[16];
    const float* c2_w1 = (const float*)d_in[17];
    const float* c2_b1 = (const float*)d_in[18];
    const float* c2_w2 = (const float*)d_in[19];
    const float* c2_b2 = (const float*)d_in[20];
    const float* rg_w1 = (const float*)d_in[21];
    const float* rg_b1 = (const float*)d_in[22];
    const float* rg_w2 = (const float*)d_in[23];
    const float* rg_b2 = (const float*)d_in[24];

    char* ws = (char*)d_ws;
    u16*   e_buf    = (u16*)  (ws);                      // 153,600,000 B (CSR order)
    u16*   x_buf    = (u16*)  (ws + 153600000);          //  25,600,000 B
    u16*   xs_buf   = (u16*)  (ws + 179200000);          //  25,600,000 B
    float* sums_buf = (float*)(ws + 204800000);          //     262,144 B
    float* cnt_buf  = (float*)(ws + 205062144);          //       2,048 B
    int*   counts   = (int*)  (ws + 205064192);          //     401,408 B
    int*   chunk_sc = (int*)  (ws + 205465600);          //     401,408 B
    int*   bsum_raw = (int*)  (ws + 205867008);          //         512 B
    int*   bsum_sc  = (int*)  (ws + 205867520);          //         512 B
    int*   src_list = (int*)  (ws + 205868032);          //   2,400,000 B
    short8* ed_w1p  = (short8*)(ws + 208268032);         //       8,192 B
    short8* ed_w2p  = (short8*)(ws + 208276224);         //      32,768 B
    short8* c1_w1p  = (short8*)(ws + 208308992);
    short8* c1_w2p  = (short8*)(ws + 208341760);
    short8* c2_w1p  = (short8*)(ws + 208374528);
    short8* c2_w2p  = (short8*)(ws + 208407296);
    short8* id_w2p  = (short8*)(ws + 208440064);
    int*   row_start = counts;    // counts dead after fill; reuse
    u16*   attr_perm = xs_buf;    // alias: attr_perm dead before first agg write

    pack_all_kernel<<<50, 256, 0, stream>>>(
        ed_w1, ed_w2, c1_w1, c1_w2, c2_w1, c2_w2, id_w2,
        ed_w1p, ed_w2p, c1_w1p, c1_w2p, c2_w1p, c2_w2p, id_w2p);

    // CSR build (fill also permutes attr to bf16 CSR order)
    hipMemsetAsync(counts, 0, 401408, stream);
    hist_kernel <<<(N_EDGES + 255) / 256, 256, 0, stream>>>(eidx, counts);
    scan1_kernel<<<N_CHUNKS, SCAN_CHUNK, 0, stream>>>(counts, chunk_sc, bsum_raw);
    scan2_kernel<<<1, 128, 0, stream>>>(bsum_raw, bsum_sc);
    fill_kernel <<<(N_EDGES + 255) / 256, 256, 0, stream>>>(eidx, chunk_sc, bsum_sc,
                                                            counts, src_list,
                                                            eattr, attr_perm);
    finalize_offsets<<<(N_NODES + 256) / 256, 256, 0, stream>>>(chunk_sc, bsum_sc, row_start);

    // front-end
    node_mlp_mfma<<<768, 256, 0, stream>>>(ids, id_w1, id_b1, id_w2p, id_b2, x_buf);
    edge_mlp_mfma<<<2048, 256, 0, stream>>>(attr_perm, ed_w1p, ed_b1, ed_w2p, ed_b2, e_buf);

    // conv 1
    aggregate_kernel<<<3125, 256, 0, stream>>>(row_start, src_list, e_buf, x_buf, xs_buf);
    conv_mlp_mfma<<<3125, 256, 0, stream>>>(xs_buf, c1_w1p, c1_b1, c1_w2p, c1_b2, x_buf);

    // conv 2
    aggregate_kernel<<<3125, 256, 0, stream>>>(row_start, src_list, e_buf, x_buf, xs_buf);
    conv_mlp_mfma<<<3125, 256, 0, stream>>>(xs_buf, c2_w1p, c2_b1, c2_w2p, c2_b2, x_buf);

    // pooling + regressor
    hipMemsetAsync(sums_buf, 0, (size_t)(NB * H + NB) * 4, stream);
    pool_kernel<<<2048, 256, 0, stream>>>(x_buf, batch, sums_buf, cnt_buf);
    regressor_kernel<<<NB, 128, 0, stream>>>(sums_buf, cnt_buf, depth,
                                             rg_w1, rg_b1, rg_w2, rg_b2, (float*)d_out);
}

// Round 7
// 414.940 us; speedup vs baseline: 1.3677x; 1.0262x over previous
//
#include <hip/hip_runtime.h>
#include <hip/hip_bf16.h>

#define N_NODES 100000
#define N_EDGES 600000
#define NB      512
#define H       128
#define ED      8
#define SCAN_CHUNK 1024
#define N_CHUNKS   98   // 98*1024 = 100352 >= N_NODES+1

typedef __attribute__((ext_vector_type(8))) short short8;
typedef __attribute__((ext_vector_type(4))) float f32x4;
typedef __attribute__((ext_vector_type(4))) unsigned int u32x4;
typedef unsigned short u16;
typedef unsigned int   u32;

static __device__ __forceinline__ u16 f2bf(float f) {
    u32 u = __float_as_uint(f);
    u32 r = u + 0x7fffu + ((u >> 16) & 1u);
    return (u16)(r >> 16);
}
static __device__ __forceinline__ float bf2f(u32 h) {
    return __uint_as_float(h << 16);
}
// packed f32->bf16 (RNE, same as f2bf): lo->bits[15:0], hi->bits[31:16]
static __device__ __forceinline__ u32 bfpack(float lo, float hi) {
    u32 r;
    asm("v_cvt_pk_bf16_f32 %0, %1, %2" : "=v"(r) : "v"(lo), "v"(hi));
    return r;
}

// ---- weight pack (ALL matrices in one launch) -----------------------------
__global__ __launch_bounds__(256) void pack_all_kernel(
    const float* __restrict__ W0, const float* __restrict__ W1,
    const float* __restrict__ W2, const float* __restrict__ W3,
    const float* __restrict__ W4, const float* __restrict__ W5,
    const float* __restrict__ W6,
    short8* __restrict__ O0, short8* __restrict__ O1,
    short8* __restrict__ O2, short8* __restrict__ O3,
    short8* __restrict__ O4, short8* __restrict__ O5,
    short8* __restrict__ O6)
{
    int gid = blockIdx.x * 256 + threadIdx.x;
    const int total = 512 + 6 * 2048;
    if (gid >= total) return;
    const float* W; short8* O; int Krows, kkmax, slot;
    if (gid < 512) { W = W0; O = O0; Krows = ED; kkmax = 1; slot = gid; }
    else {
        int m = (gid - 512) / 2048;
        slot = (gid - 512) % 2048;
        Krows = H; kkmax = 4;
        switch (m) {
            case 0: W = W1; O = O1; break;
            case 1: W = W2; O = O2; break;
            case 2: W = W3; O = O3; break;
            case 3: W = W4; O = O4; break;
            case 4: W = W5; O = O5; break;
            default: W = W6; O = O6; break;
        }
    }
    int lane = slot & 63;
    int t = slot >> 6;
    int nt = t & 1; t >>= 1;
    int kk = t % kkmax;
    int w  = t / kkmax;
    int quad = lane >> 4, n15 = lane & 15;
    int n = w * 32 + nt * 16 + n15;
    short8 v;
    #pragma unroll
    for (int j = 0; j < 8; j++) {
        int k = kk * 32 + quad * 8 + j;
        v[j] = (k < Krows) ? (short)f2bf(W[k * H + n]) : (short)0;
    }
    O[slot] = v;
}

// ---------------- CSR build ------------------------------------------------
__global__ __launch_bounds__(256) void hist_kernel(
    const int* __restrict__ edge_index, int* __restrict__ counts)
{
    int e = blockIdx.x * 256 + threadIdx.x;
    if (e < N_EDGES) atomicAdd(&counts[edge_index[N_EDGES + e]], 1);
}

__global__ __launch_bounds__(SCAN_CHUNK) void scan1_kernel(
    const int* __restrict__ counts, int* __restrict__ chunk_scan,
    int* __restrict__ bsum_raw)
{
    __shared__ int s[SCAN_CHUNK];
    int tid = threadIdx.x;
    int gid = blockIdx.x * SCAN_CHUNK + tid;
    int v = counts[gid];
    s[tid] = v;
    __syncthreads();
    #pragma unroll
    for (int off = 1; off < SCAN_CHUNK; off <<= 1) {
        int t = (tid >= off) ? s[tid - off] : 0;
        __syncthreads();
        s[tid] += t;
        __syncthreads();
    }
    chunk_scan[gid] = s[tid] - v;
    if (tid == SCAN_CHUNK - 1) bsum_raw[blockIdx.x] = s[tid];
}

__global__ __launch_bounds__(128) void scan2_kernel(
    const int* __restrict__ bsum_raw, int* __restrict__ bsum_scan)
{
    __shared__ int s[128];
    int tid = threadIdx.x;
    int v = (tid < N_CHUNKS) ? bsum_raw[tid] : 0;
    s[tid] = v;
    __syncthreads();
    #pragma unroll
    for (int off = 1; off < 128; off <<= 1) {
        int t = (tid >= off) ? s[tid - off] : 0;
        __syncthreads();
        s[tid] += t;
        __syncthreads();
    }
    bsum_scan[tid] = s[tid] - v;
}

// fill: src_list[pos]=src (CSR order); attr_perm[pos]=bf16(attr[e]) (CSR order)
__global__ __launch_bounds__(256) void fill_kernel(
    const int* __restrict__ edge_index,
    const int* __restrict__ chunk_scan, const int* __restrict__ bsum_scan,
    int* __restrict__ counts, int* __restrict__ src_list,
    const float* __restrict__ attr, u16* __restrict__ attr_perm)
{
    int e = blockIdx.x * 256 + threadIdx.x;
    if (e >= N_EDGES) return;
    int src = edge_index[e];
    int dst = edge_index[N_EDGES + e];
    int slot = atomicAdd(&counts[dst], -1) - 1;
    int pos = chunk_scan[dst] + bsum_scan[dst >> 10] + slot;
    src_list[pos] = src;
    float4 v0 = *(const float4*)&attr[(long)e * ED];
    float4 v1 = *(const float4*)&attr[(long)e * ED + 4];
    u32 w0 = bfpack(v0.x, v0.y);
    u32 w1 = bfpack(v0.z, v0.w);
    u32 w2 = bfpack(v1.x, v1.y);
    u32 w3 = bfpack(v1.z, v1.w);
    *(uint4*)&attr_perm[(long)pos * ED] = make_uint4(w0, w1, w2, w3);
}

// row_start[n] = chunk_scan[n] + bsum_scan[n>>10]   (n in [0, N])
__global__ __launch_bounds__(256) void finalize_offsets(
    const int* __restrict__ chunk_scan, const int* __restrict__ bsum_scan,
    int* __restrict__ row_start)
{
    int i = blockIdx.x * 256 + threadIdx.x;
    if (i <= N_NODES) row_start[i] = chunk_scan[i] + bsum_scan[i >> 10];
}

// ---------------- node MLP (MFMA layer2): x bf16 [N,H] ---------------------
__global__ __launch_bounds__(256) void node_mlp_mfma(
    const int* __restrict__ ids,
    const float* __restrict__ w1, const float* __restrict__ b1,
    const short8* __restrict__ pW2, const float* __restrict__ b2,
    u16* __restrict__ x_out)
{
    __shared__ u16 sH[64 * 136];
    __shared__ float s_x0[64];
    int tid = threadIdx.x;
    int w = tid >> 6, lane = tid & 63, quad = lane >> 4, n15 = lane & 15;
    short8 fW2[4][2];
    #pragma unroll
    for (int kk = 0; kk < 4; kk++) {
        fW2[kk][0] = pW2[((w * 4 + kk) * 2 + 0) * 64 + lane];
        fW2[kk][1] = pW2[((w * 4 + kk) * 2 + 1) * 64 + lane];
    }
    float rb2[2] = { b2[w * 32 + n15], b2[w * 32 + 16 + n15] };
    float w1c = w1[tid & 127], b1c = b1[tid & 127];
    const int ntile = (N_NODES + 63) / 64;
    for (int tile = blockIdx.x; tile < ntile; tile += gridDim.x) {
        int row0 = tile * 64;
        if (tid < 64) {
            int n = row0 + tid;
            float x0 = (n < N_NODES) ? (float)ids[n] / 281474976710655.0f : 0.0f;
            s_x0[tid] = fminf(fmaxf(x0, 0.0f), 1.0f);
        }
        __syncthreads();
        int half = tid >> 7, c = tid & 127;
        #pragma unroll
        for (int rr = 0; rr < 32; rr += 2) {
            int r = half + rr * 2;
            u32 p = bfpack(fmaxf(s_x0[r] * w1c + b1c, 0.0f),
                           fmaxf(s_x0[r + 2] * w1c + b1c, 0.0f));
            sH[r * 136 + c]       = (u16)p;
            sH[(r + 2) * 136 + c] = (u16)(p >> 16);
        }
        __syncthreads();
        f32x4 acc[4][2];
        #pragma unroll
        for (int s = 0; s < 4; s++) { acc[s][0] = (f32x4){0,0,0,0}; acc[s][1] = (f32x4){0,0,0,0}; }
        #pragma unroll
        for (int kk = 0; kk < 4; kk++) {
            #pragma unroll
            for (int s = 0; s < 4; s++) {
                short8 a = *(const short8*)&sH[(s * 16 + n15) * 136 + kk * 32 + quad * 8];
                acc[s][0] = __builtin_amdgcn_mfma_f32_16x16x32_bf16(a, fW2[kk][0], acc[s][0], 0, 0, 0);
                acc[s][1] = __builtin_amdgcn_mfma_f32_16x16x32_bf16(a, fW2[kk][1], acc[s][1], 0, 0, 0);
            }
        }
        __syncthreads();
        #pragma unroll
        for (int s = 0; s < 4; s++)
            #pragma unroll
            for (int nt = 0; nt < 2; nt++) {
                int col = w * 32 + nt * 16 + n15;
                int rb = (s * 16 + quad * 4) * 136 + col;
                u32 p0 = bfpack(acc[s][nt][0] + rb2[nt], acc[s][nt][1] + rb2[nt]);
                u32 p1 = bfpack(acc[s][nt][2] + rb2[nt], acc[s][nt][3] + rb2[nt]);
                sH[rb]       = (u16)p0;
                sH[rb + 136] = (u16)(p0 >> 16);
                sH[rb + 272] = (u16)p1;
                sH[rb + 408] = (u16)(p1 >> 16);
            }
        __syncthreads();
        for (int idx = tid; idx < 64 * 16; idx += 256) {
            int r = idx >> 4, c8 = (idx & 15) << 3;
            int n = row0 + r;
            if (n < N_NODES)
                *(uint4*)&x_out[(long)n * H + c8] = *(const uint4*)&sH[r * 136 + c8];
        }
        __syncthreads();
    }
}

// ---- edge MLP v3: linear stream (CSR-ordered attr in, linear e out) -------
// A-fragments load straight from global (K=32 with cols 8..31 == 0, so only
// quad-0 lanes carry data). No sA, no pos scatter. LDS = sH only (17.4 KB).
__global__ __launch_bounds__(256) void edge_mlp_mfma(
    const u16* __restrict__ attr_perm,
    const short8* __restrict__ pW1, const float* __restrict__ b1,
    const short8* __restrict__ pW2, const float* __restrict__ b2,
    u16* __restrict__ e_perm)
{
    __shared__ u16 sH[64 * 136];
    int tid = threadIdx.x;
    int w = tid >> 6, lane = tid & 63, quad = lane >> 4, n15 = lane & 15;
    short8 fW1[2];
    fW1[0] = pW1[(w * 2 + 0) * 64 + lane];
    fW1[1] = pW1[(w * 2 + 1) * 64 + lane];
    short8 fW2[4][2];
    #pragma unroll
    for (int kk = 0; kk < 4; kk++) {
        fW2[kk][0] = pW2[((w * 4 + kk) * 2 + 0) * 64 + lane];
        fW2[kk][1] = pW2[((w * 4 + kk) * 2 + 1) * 64 + lane];
    }
    float rb1[2] = { b1[w * 32 + n15], b1[w * 32 + 16 + n15] };
    float rb2[2] = { b2[w * 32 + n15], b2[w * 32 + 16 + n15] };
    const short8 zero8 = (short8){0,0,0,0,0,0,0,0};
    const int ntile = N_EDGES / 64;   // 9375 exact
    for (int tile = blockIdx.x; tile < ntile; tile += gridDim.x) {
        int row0 = tile * 64;
        // A-fragments: quad 0 holds attr cols 0..7; quads 1..3 are zero pad
        short8 av[4];
        #pragma unroll
        for (int s = 0; s < 4; s++) {
            av[s] = zero8;
            if (quad == 0)
                av[s] = *(const short8*)&attr_perm[(long)(row0 + s * 16 + n15) * ED];
        }
        // GEMM1 (K=32, one step)
        f32x4 acc[4][2];
        #pragma unroll
        for (int s = 0; s < 4; s++) { acc[s][0] = (f32x4){0,0,0,0}; acc[s][1] = (f32x4){0,0,0,0}; }
        #pragma unroll
        for (int s = 0; s < 4; s++) {
            acc[s][0] = __builtin_amdgcn_mfma_f32_16x16x32_bf16(av[s], fW1[0], acc[s][0], 0, 0, 0);
            acc[s][1] = __builtin_amdgcn_mfma_f32_16x16x32_bf16(av[s], fW1[1], acc[s][1], 0, 0, 0);
        }
        #pragma unroll
        for (int s = 0; s < 4; s++)
            #pragma unroll
            for (int nt = 0; nt < 2; nt++) {
                int col = w * 32 + nt * 16 + n15;
                int rb = (s * 16 + quad * 4) * 136 + col;
                u32 p0 = bfpack(fmaxf(acc[s][nt][0] + rb1[nt], 0.0f),
                                fmaxf(acc[s][nt][1] + rb1[nt], 0.0f));
                u32 p1 = bfpack(fmaxf(acc[s][nt][2] + rb1[nt], 0.0f),
                                fmaxf(acc[s][nt][3] + rb1[nt], 0.0f));
                sH[rb]       = (u16)p0;
                sH[rb + 136] = (u16)(p0 >> 16);
                sH[rb + 272] = (u16)p1;
                sH[rb + 408] = (u16)(p1 >> 16);
            }
        __syncthreads();
        // GEMM2 (K=128)
        #pragma unroll
        for (int s = 0; s < 4; s++) { acc[s][0] = (f32x4){0,0,0,0}; acc[s][1] = (f32x4){0,0,0,0}; }
        #pragma unroll
        for (int kk = 0; kk < 4; kk++) {
            #pragma unroll
            for (int s = 0; s < 4; s++) {
                short8 a = *(const short8*)&sH[(s * 16 + n15) * 136 + kk * 32 + quad * 8];
                acc[s][0] = __builtin_amdgcn_mfma_f32_16x16x32_bf16(a, fW2[kk][0], acc[s][0], 0, 0, 0);
                acc[s][1] = __builtin_amdgcn_mfma_f32_16x16x32_bf16(a, fW2[kk][1], acc[s][1], 0, 0, 0);
            }
        }
        __syncthreads();
        #pragma unroll
        for (int s = 0; s < 4; s++)
            #pragma unroll
            for (int nt = 0; nt < 2; nt++) {
                int col = w * 32 + nt * 16 + n15;
                int rb = (s * 16 + quad * 4) * 136 + col;
                u32 p0 = bfpack(acc[s][nt][0] + rb2[nt], acc[s][nt][1] + rb2[nt]);
                u32 p1 = bfpack(acc[s][nt][2] + rb2[nt], acc[s][nt][3] + rb2[nt]);
                sH[rb]       = (u16)p0;
                sH[rb + 136] = (u16)(p0 >> 16);
                sH[rb + 272] = (u16)p1;
                sH[rb + 408] = (u16)(p1 >> 16);
            }
        __syncthreads();
        // linear coalesced store
        for (int idx = tid; idx < 64 * 16; idx += 256) {
            int r = idx >> 4, c8 = (idx & 15) << 3;
            *(uint4*)&e_perm[(long)(row0 + r) * H + c8] = *(const uint4*)&sH[r * 136 + c8];
        }
        __syncthreads();
    }
}

// ---- aggregate (r3-proven): 16-lane group per node, dwordx4 row loads -----
// lane owns 8 cols; 4 nodes per wave; 6250 blocks x 16 nodes = 100000 exact.
static __device__ __forceinline__ void acc8(float* a, u32x4 xv, u32x4 ev) {
    #pragma unroll
    for (int q = 0; q < 4; q++) {
        a[2 * q + 0] += fmaxf(bf2f(xv[q] & 0xffff) + bf2f(ev[q] & 0xffff), 0.0f);
        a[2 * q + 1] += fmaxf(bf2f(xv[q] >> 16)    + bf2f(ev[q] >> 16),    0.0f);
    }
}

__global__ __launch_bounds__(256) void aggregate_kernel(
    const int* __restrict__ row_start,
    const int* __restrict__ src_list,
    const u16* __restrict__ e_perm,
    const u16* __restrict__ x,
    u16* __restrict__ xs_out)
{
    int tid  = threadIdx.x;
    int lane = tid & 63;
    int l16  = lane & 15;
    int base = lane & 48;            // group base lane within wave
    int fo   = l16 * 8;              // 8 u16 cols per lane
    int n = blockIdx.x * 16 + (tid >> 4);   // exact: 6250*16 = 100000
    const u16* xb = x + fo;

    int beg = row_start[n];
    int end = row_start[n + 1];
    float a[8], b[8];
    #pragma unroll
    for (int q = 0; q < 8; q++) { a[q] = 0.0f; b[q] = 0.0f; }

    for (int j0 = beg; j0 < end; j0 += 16) {
        int m = min(16, end - j0);
        int sv = src_list[j0 + min(l16, m - 1)];
        const u16* ej = e_perm + (long)j0 * H + fo;
        int j = 0;
        for (; j + 2 <= m; j += 2) {
            int s0 = __shfl(sv, base | j);
            int s1 = __shfl(sv, base | (j + 1));
            u32x4 xv0 = *(const u32x4*)(xb + (long)s0 * H);
            u32x4 ev0 = *(const u32x4*)(ej + (long)(j + 0) * H);
            u32x4 xv1 = *(const u32x4*)(xb + (long)s1 * H);
            u32x4 ev1 = *(const u32x4*)(ej + (long)(j + 1) * H);
            acc8(a, xv0, ev0);
            acc8(b, xv1, ev1);
        }
        if (j < m) {
            int s0 = __shfl(sv, base | j);
            u32x4 xv0 = *(const u32x4*)(xb + (long)s0 * H);
            u32x4 ev0 = *(const u32x4*)(ej + (long)j * H);
            acc8(a, xv0, ev0);
        }
    }
    // self + combine + pack
    u32x4 xself = *(const u32x4*)(xb + (long)n * H);
    u32x4 out;
    #pragma unroll
    for (int q = 0; q < 4; q++) {
        float o0 = bf2f(xself[q] & 0xffff) + a[2 * q + 0] + b[2 * q + 0];
        float o1 = bf2f(xself[q] >> 16)    + a[2 * q + 1] + b[2 * q + 1];
        out[q] = bfpack(o0, o1);
    }
    *(u32x4*)&xs_out[(long)n * H + fo] = out;
}

// ---- conv MLP: 32-row tiles, single LDS buffer, high block count ----------
__global__ __launch_bounds__(256) void conv_mlp_mfma(
    const u16* __restrict__ xs,
    const short8* __restrict__ pW1, const float* __restrict__ b1,
    const short8* __restrict__ pW2, const float* __restrict__ b2,
    u16* __restrict__ x_out)
{
    __shared__ u16 sA[32 * 136];
    int tid = threadIdx.x;
    int w = tid >> 6, lane = tid & 63, quad = lane >> 4, n15 = lane & 15;
    short8 fW1[4][2], fW2[4][2];
    #pragma unroll
    for (int kk = 0; kk < 4; kk++) {
        fW1[kk][0] = pW1[((w * 4 + kk) * 2 + 0) * 64 + lane];
        fW1[kk][1] = pW1[((w * 4 + kk) * 2 + 1) * 64 + lane];
        fW2[kk][0] = pW2[((w * 4 + kk) * 2 + 0) * 64 + lane];
        fW2[kk][1] = pW2[((w * 4 + kk) * 2 + 1) * 64 + lane];
    }
    float rb1[2] = { b1[w * 32 + n15], b1[w * 32 + 16 + n15] };
    float rb2[2] = { b2[w * 32 + n15], b2[w * 32 + 16 + n15] };
    const int ntile = N_NODES / 32;   // 3125 exact
    for (int tile = blockIdx.x; tile < ntile; tile += gridDim.x) {
        long row0 = (long)tile * 32;
        for (int idx = tid; idx < 32 * 16; idx += 256) {
            int r = idx >> 4, c8 = (idx & 15) << 3;
            *(uint4*)&sA[r * 136 + c8] = *(const uint4*)&xs[(row0 + r) * H + c8];
        }
        __syncthreads();
        // GEMM1
        f32x4 acc[2][2];
        #pragma unroll
        for (int s = 0; s < 2; s++) { acc[s][0] = (f32x4){0,0,0,0}; acc[s][1] = (f32x4){0,0,0,0}; }
        #pragma unroll
        for (int kk = 0; kk < 4; kk++) {
            #pragma unroll
            for (int s = 0; s < 2; s++) {
                short8 a = *(const short8*)&sA[(s * 16 + n15) * 136 + kk * 32 + quad * 8];
                acc[s][0] = __builtin_amdgcn_mfma_f32_16x16x32_bf16(a, fW1[kk][0], acc[s][0], 0, 0, 0);
                acc[s][1] = __builtin_amdgcn_mfma_f32_16x16x32_bf16(a, fW1[kk][1], acc[s][1], 0, 0, 0);
            }
        }
        __syncthreads();   // all sA reads done
        #pragma unroll
        for (int s = 0; s < 2; s++)
            #pragma unroll
            for (int nt = 0; nt < 2; nt++) {
                int col = w * 32 + nt * 16 + n15;
                int rb = (s * 16 + quad * 4) * 136 + col;
                u32 p0 = bfpack(fmaxf(acc[s][nt][0] + rb1[nt], 0.0f),
                                fmaxf(acc[s][nt][1] + rb1[nt], 0.0f));
                u32 p1 = bfpack(fmaxf(acc[s][nt][2] + rb1[nt], 0.0f),
                                fmaxf(acc[s][nt][3] + rb1[nt], 0.0f));
                sA[rb]       = (u16)p0;
                sA[rb + 136] = (u16)(p0 >> 16);
                sA[rb + 272] = (u16)p1;
                sA[rb + 408] = (u16)(p1 >> 16);
            }
        __syncthreads();
        // GEMM2
        #pragma unroll
        for (int s = 0; s < 2; s++) { acc[s][0] = (f32x4){0,0,0,0}; acc[s][1] = (f32x4){0,0,0,0}; }
        #pragma unroll
        for (int kk = 0; kk < 4; kk++) {
            #pragma unroll
            for (int s = 0; s < 2; s++) {
                short8 a = *(const short8*)&sA[(s * 16 + n15) * 136 + kk * 32 + quad * 8];
                acc[s][0] = __builtin_amdgcn_mfma_f32_16x16x32_bf16(a, fW2[kk][0], acc[s][0], 0, 0, 0);
                acc[s][1] = __builtin_amdgcn_mfma_f32_16x16x32_bf16(a, fW2[kk][1], acc[s][1], 0, 0, 0);
            }
        }
        __syncthreads();   // all sA reads done
        #pragma unroll
        for (int s = 0; s < 2; s++)
            #pragma unroll
            for (int nt = 0; nt < 2; nt++) {
                int col = w * 32 + nt * 16 + n15;
                int rb = (s * 16 + quad * 4) * 136 + col;
                u32 p0 = bfpack(fmaxf(acc[s][nt][0] + rb2[nt], 0.0f),
                                fmaxf(acc[s][nt][1] + rb2[nt], 0.0f));
                u32 p1 = bfpack(fmaxf(acc[s][nt][2] + rb2[nt], 0.0f),
                                fmaxf(acc[s][nt][3] + rb2[nt], 0.0f));
                sA[rb]       = (u16)p0;
                sA[rb + 136] = (u16)(p0 >> 16);
                sA[rb + 272] = (u16)p1;
                sA[rb + 408] = (u16)(p1 >> 16);
            }
        __syncthreads();
        for (int idx = tid; idx < 32 * 16; idx += 256) {
            int r = idx >> 4, c8 = (idx & 15) << 3;
            *(uint4*)&x_out[(row0 + r) * H + c8] = *(const uint4*)&sA[r * 136 + c8];
        }
        __syncthreads();
    }
}

// ---------------- mean-pool: vectorized, high-TLP, segment flush -----------
__global__ __launch_bounds__(256) void pool_kernel(
    const u16* __restrict__ x, const int* __restrict__ batch,
    float* __restrict__ sums, float* __restrict__ cnt)
{
    int sg   = threadIdx.x >> 6;
    int lane = threadIdx.x & 63;
    int fo = lane * 2;
    const int nper = (N_NODES + gridDim.x - 1) / gridDim.x;
    int n0 = blockIdx.x * nper;
    int n1 = min(n0 + nper, N_NODES);
    int cur = -1;
    float a0 = 0.0f, a1 = 0.0f, c = 0.0f;
    for (int n = n0 + sg; n < n1; n += 4) {
        int b = batch[n];
        if (b != cur) {
            if (cur >= 0) {
                atomicAdd(&sums[cur * H + fo],     a0);
                atomicAdd(&sums[cur * H + fo + 1], a1);
                if (lane == 0) atomicAdd(&cnt[cur], c);
            }
            a0 = a1 = 0.0f; c = 0.0f; cur = b;
        }
        u32 xv = *(const u32*)&x[(long)n * H + fo];
        a0 += bf2f(xv & 0xffff);
        a1 += bf2f(xv >> 16);
        c += 1.0f;
    }
    if (cur >= 0) {
        atomicAdd(&sums[cur * H + fo],     a0);
        atomicAdd(&sums[cur * H + fo + 1], a1);
        if (lane == 0) atomicAdd(&cnt[cur], c);
    }
}

// ---------------- regressor ------------------------------------------------
__global__ __launch_bounds__(128) void regressor_kernel(
    const float* __restrict__ sums, const float* __restrict__ cnt,
    const float* __restrict__ depth,
    const float* __restrict__ w1, const float* __restrict__ b1,
    const float* __restrict__ w2, const float* __restrict__ b2,
    float* __restrict__ out)
{
    __shared__ float s_mean[H];
    __shared__ float s_red[2];
    int b = blockIdx.x;
    int j = threadIdx.x;
    float c = fmaxf(cnt[b], 1.0f);
    s_mean[j] = sums[b * H + j] / c;
    __syncthreads();
    float h = b1[j];
    #pragma unroll 8
    for (int k = 0; k < H; k++) h += s_mean[k] * w1[k * H + j];
    h += depth[b] * w1[H * H + j];
    h = fmaxf(h, 0.0f);
    float p = h * w2[j];
    #pragma unroll
    for (int off = 32; off >= 1; off >>= 1) p += __shfl_down(p, off, 64);
    if ((j & 63) == 0) s_red[j >> 6] = p;
    __syncthreads();
    if (j == 0) out[b] = s_red[0] + s_red[1] + b2[0];
}

extern "C" void kernel_launch(void* const* d_in, const int* in_sizes, int n_in,
                              void* d_out, int out_size, void* d_ws, size_t ws_size,
                              hipStream_t stream)
{
    const int*   ids   = (const int*)  d_in[0];
    const int*   eidx  = (const int*)  d_in[1];
    const float* eattr = (const float*)d_in[2];
    const int*   batch = (const int*)  d_in[3];
    const float* depth = (const float*)d_in[4];
    const float* id_w1 = (const float*)d_in[5];
    const float* id_b1 = (const float*)d_in[6];
    const float* id_w2 = (const float*)d_in[7];
    const float* id_b2 = (const float*)d_in[8];
    const float* ed_w1 = (const float*)d_in[9];
    const float* ed_b1 = (const float*)d_in[10];
    const float* ed_w2 = (const float*)d_in[11];
    const float* ed_b2 = (const float*)d_in[12];
    const float* c1_w1 = (const float*)d_in[13];
    const float* c1_b1 = (const float*)d_in[14];
    const float* c1_w2 = (const float*)d_in[15];
    const float* c1_b2 = (const float*)d_in[16];
    const float* c2_w1 = (const float*)d_in[17];
    const float* c2_b1 = (const float*)d_in[18];
    const float* c2_w2 = (const float*)d_in[19];
    const float* c2_b2 = (const float*)d_in[20];
    const float* rg_w1 = (const float*)d_in[21];
    const float* rg_b1 = (const float*)d_in[22];
    const float* rg_w2 = (const float*)d_in[23];
    const float* rg_b2 = (const float*)d_in[24];

    char* ws = (char*)d_ws;
    u16*   e_buf    = (u16*)  (ws);                      // 153,600,000 B (CSR order)
    u16*   x_buf    = (u16*)  (ws + 153600000);          //  25,600,000 B
    u16*   xs_buf   = (u16*)  (ws + 179200000);          //  25,600,000 B
    float* sums_buf = (float*)(ws + 204800000);          //     262,144 B
    float* cnt_buf  = (float*)(ws + 205062144);          //       2,048 B
    int*   counts   = (int*)  (ws + 205064192);          //     401,408 B
    int*   chunk_sc = (int*)  (ws + 205465600);          //     401,408 B
    int*   bsum_raw = (int*)  (ws + 205867008);          //         512 B
    int*   bsum_sc  = (int*)  (ws + 205867520);          //         512 B
    int*   src_list = (int*)  (ws + 205868032);          //   2,400,000 B
    short8* ed_w1p  = (short8*)(ws + 208268032);         //       8,192 B
    short8* ed_w2p  = (short8*)(ws + 208276224);         //      32,768 B
    short8* c1_w1p  = (short8*)(ws + 208308992);
    short8* c1_w2p  = (short8*)(ws + 208341760);
    short8* c2_w1p  = (short8*)(ws + 208374528);
    short8* c2_w2p  = (short8*)(ws + 208407296);
    short8* id_w2p  = (short8*)(ws + 208440064);
    int*   row_start = counts;    // counts dead after fill; reuse
    u16*   attr_perm = xs_buf;    // alias: attr_perm dead before first agg write

    pack_all_kernel<<<50, 256, 0, stream>>>(
        ed_w1, ed_w2, c1_w1, c1_w2, c2_w1, c2_w2, id_w2,
        ed_w1p, ed_w2p, c1_w1p, c1_w2p, c2_w1p, c2_w2p, id_w2p);

    // CSR build (fill also permutes attr to bf16 CSR order)
    hipMemsetAsync(counts, 0, 401408, stream);
    hist_kernel <<<(N_EDGES + 255) / 256, 256, 0, stream>>>(eidx, counts);
    scan1_kernel<<<N_CHUNKS, SCAN_CHUNK, 0, stream>>>(counts, chunk_sc, bsum_raw);
    scan2_kernel<<<1, 128, 0, stream>>>(bsum_raw, bsum_sc);
    fill_kernel <<<(N_EDGES + 255) / 256, 256, 0, stream>>>(eidx, chunk_sc, bsum_sc,
                                                            counts, src_list,
                                                            eattr, attr_perm);
    finalize_offsets<<<(N_NODES + 256) / 256, 256, 0, stream>>>(chunk_sc, bsum_sc, row_start);

    // front-end
    node_mlp_mfma<<<768, 256, 0, stream>>>(ids, id_w1, id_b1, id_w2p, id_b2, x_buf);
    edge_mlp_mfma<<<2048, 256, 0, stream>>>(attr_perm, ed_w1p, ed_b1, ed_w2p, ed_b2, e_buf);

    // conv 1
    aggregate_kernel<<<6250, 256, 0, stream>>>(row_start, src_list, e_buf, x_buf, xs_buf);
    conv_mlp_mfma<<<3125, 256, 0, stream>>>(xs_buf, c1_w1p, c1_b1, c1_w2p, c1_b2, x_buf);

    // conv 2
    aggregate_kernel<<<6250, 256, 0, stream>>>(row_start, src_list, e_buf, x_buf, xs_buf);
    conv_mlp_mfma<<<3125, 256, 0, stream>>>(xs_buf, c2_w1p, c2_b1, c2_w2p, c2_b2, x_buf);

    // pooling + regressor
    hipMemsetAsync(sums_buf, 0, (size_t)(NB * H + NB) * 4, stream);
    pool_kernel<<<2048, 256, 0, stream>>>(x_buf, batch, sums_buf, cnt_buf);
    regressor_kernel<<<NB, 128, 0, stream>>>(sums_buf, cnt_buf, depth,
                                             rg_w1, rg_b1, rg_w2, rg_b2, (float*)d_out);
}

// Round 8
// 393.292 us; speedup vs baseline: 1.4430x; 1.0550x over previous
//
#include <hip/hip_runtime.h>
#include <hip/hip_bf16.h>

#define N_NODES 100000
#define N_EDGES 600000
#define NB      512
#define H       128
#define ED      8
#define SCAN_CHUNK 1024
#define N_CHUNKS   98   // 98*1024 = 100352 >= N_NODES+1

typedef __attribute__((ext_vector_type(8))) short short8;
typedef __attribute__((ext_vector_type(4))) float f32x4;
typedef __attribute__((ext_vector_type(4))) unsigned int u32x4;
typedef unsigned short u16;
typedef unsigned int   u32;

static __device__ __forceinline__ u16 f2bf(float f) {
    u32 u = __float_as_uint(f);
    u32 r = u + 0x7fffu + ((u >> 16) & 1u);
    return (u16)(r >> 16);
}
static __device__ __forceinline__ float bf2f(u32 h) {
    return __uint_as_float(h << 16);
}
// packed f32->bf16 (RNE, same as f2bf): lo->bits[15:0], hi->bits[31:16]
static __device__ __forceinline__ u32 bfpack(float lo, float hi) {
    u32 r;
    asm("v_cvt_pk_bf16_f32 %0, %1, %2" : "=v"(r) : "v"(lo), "v"(hi));
    return r;
}

// ---- fused: weight pack (blocks 0..49) + degree histogram (blocks 50+) ----
__global__ __launch_bounds__(256) void pack_hist_kernel(
    const float* __restrict__ W0, const float* __restrict__ W1,
    const float* __restrict__ W2, const float* __restrict__ W3,
    const float* __restrict__ W4, const float* __restrict__ W5,
    const float* __restrict__ W6,
    short8* __restrict__ O0, short8* __restrict__ O1,
    short8* __restrict__ O2, short8* __restrict__ O3,
    short8* __restrict__ O4, short8* __restrict__ O5,
    short8* __restrict__ O6,
    const int* __restrict__ edge_index, int* __restrict__ counts)
{
    if (blockIdx.x >= 50) {
        int e = (blockIdx.x - 50) * 256 + threadIdx.x;
        if (e < N_EDGES) atomicAdd(&counts[edge_index[N_EDGES + e]], 1);
        return;
    }
    int gid = blockIdx.x * 256 + threadIdx.x;   // < 12800 exactly
    const float* W; short8* O; int Krows, kkmax, slot;
    if (gid < 512) { W = W0; O = O0; Krows = ED; kkmax = 1; slot = gid; }
    else {
        int m = (gid - 512) / 2048;
        slot = (gid - 512) % 2048;
        Krows = H; kkmax = 4;
        switch (m) {
            case 0: W = W1; O = O1; break;
            case 1: W = W2; O = O2; break;
            case 2: W = W3; O = O3; break;
            case 3: W = W4; O = O4; break;
            case 4: W = W5; O = O5; break;
            default: W = W6; O = O6; break;
        }
    }
    int lane = slot & 63;
    int t = slot >> 6;
    int nt = t & 1; t >>= 1;
    int kk = t % kkmax;
    int w  = t / kkmax;
    int quad = lane >> 4, n15 = lane & 15;
    int n = w * 32 + nt * 16 + n15;
    short8 v;
    #pragma unroll
    for (int j = 0; j < 8; j++) {
        int k = kk * 32 + quad * 8 + j;
        v[j] = (k < Krows) ? (short)f2bf(W[k * H + n]) : (short)0;
    }
    O[slot] = v;
}

// ---- fused: per-chunk scan (blocks 0..97, 256 thr x 4 elems) + node MLP ---
__global__ __launch_bounds__(256) void scan_node_kernel(
    const int* __restrict__ counts, int* __restrict__ chunk_scan,
    int* __restrict__ bsum_raw,
    const int* __restrict__ ids,
    const float* __restrict__ w1, const float* __restrict__ b1,
    const short8* __restrict__ pW2, const float* __restrict__ b2,
    u16* __restrict__ x_out)
{
    __shared__ u16 sH[64 * 136];
    __shared__ float s_x0[64];
    __shared__ int sS[256];
    int tid = threadIdx.x;

    if (blockIdx.x < N_CHUNKS) {
        // ---- scan1: 1024-elem chunk, 4 elems/thread ----
        int base = blockIdx.x * SCAN_CHUNK + tid * 4;
        int4 v = *(const int4*)&counts[base];
        int q0 = v.x, q1 = q0 + v.y, q2 = q1 + v.z, q3 = q2 + v.w;
        sS[tid] = q3;
        __syncthreads();
        #pragma unroll
        for (int off = 1; off < 256; off <<= 1) {
            int t = (tid >= off) ? sS[tid - off] : 0;
            __syncthreads();
            sS[tid] += t;
            __syncthreads();
        }
        int excl = sS[tid] - q3;
        int4 o;
        o.x = excl; o.y = excl + q0; o.z = excl + q1; o.w = excl + q2;
        *(int4*)&chunk_scan[base] = o;
        if (tid == 255) bsum_raw[blockIdx.x] = sS[255];
        return;
    }

    // ---- node MLP on blocks 98..865 (768 blocks) ----
    int bid = blockIdx.x - N_CHUNKS;
    int w = tid >> 6, lane = tid & 63, quad = lane >> 4, n15 = lane & 15;
    short8 fW2[4][2];
    #pragma unroll
    for (int kk = 0; kk < 4; kk++) {
        fW2[kk][0] = pW2[((w * 4 + kk) * 2 + 0) * 64 + lane];
        fW2[kk][1] = pW2[((w * 4 + kk) * 2 + 1) * 64 + lane];
    }
    float rb2[2] = { b2[w * 32 + n15], b2[w * 32 + 16 + n15] };
    float w1c = w1[tid & 127], b1c = b1[tid & 127];
    const int ntile = (N_NODES + 63) / 64;
    for (int tile = bid; tile < ntile; tile += 768) {
        int row0 = tile * 64;
        if (tid < 64) {
            int n = row0 + tid;
            float x0 = (n < N_NODES) ? (float)ids[n] / 281474976710655.0f : 0.0f;
            s_x0[tid] = fminf(fmaxf(x0, 0.0f), 1.0f);
        }
        __syncthreads();
        int half = tid >> 7, c = tid & 127;
        #pragma unroll
        for (int rr = 0; rr < 32; rr += 2) {
            int r = half + rr * 2;
            u32 p = bfpack(fmaxf(s_x0[r] * w1c + b1c, 0.0f),
                           fmaxf(s_x0[r + 2] * w1c + b1c, 0.0f));
            sH[r * 136 + c]       = (u16)p;
            sH[(r + 2) * 136 + c] = (u16)(p >> 16);
        }
        __syncthreads();
        f32x4 acc[4][2];
        #pragma unroll
        for (int s = 0; s < 4; s++) { acc[s][0] = (f32x4){0,0,0,0}; acc[s][1] = (f32x4){0,0,0,0}; }
        #pragma unroll
        for (int kk = 0; kk < 4; kk++) {
            #pragma unroll
            for (int s = 0; s < 4; s++) {
                short8 a = *(const short8*)&sH[(s * 16 + n15) * 136 + kk * 32 + quad * 8];
                acc[s][0] = __builtin_amdgcn_mfma_f32_16x16x32_bf16(a, fW2[kk][0], acc[s][0], 0, 0, 0);
                acc[s][1] = __builtin_amdgcn_mfma_f32_16x16x32_bf16(a, fW2[kk][1], acc[s][1], 0, 0, 0);
            }
        }
        __syncthreads();
        #pragma unroll
        for (int s = 0; s < 4; s++)
            #pragma unroll
            for (int nt = 0; nt < 2; nt++) {
                int col = w * 32 + nt * 16 + n15;
                int rb = (s * 16 + quad * 4) * 136 + col;
                u32 p0 = bfpack(acc[s][nt][0] + rb2[nt], acc[s][nt][1] + rb2[nt]);
                u32 p1 = bfpack(acc[s][nt][2] + rb2[nt], acc[s][nt][3] + rb2[nt]);
                sH[rb]       = (u16)p0;
                sH[rb + 136] = (u16)(p0 >> 16);
                sH[rb + 272] = (u16)p1;
                sH[rb + 408] = (u16)(p1 >> 16);
            }
        __syncthreads();
        for (int idx = tid; idx < 64 * 16; idx += 256) {
            int r = idx >> 4, c8 = (idx & 15) << 3;
            int n = row0 + r;
            if (n < N_NODES)
                *(uint4*)&x_out[(long)n * H + c8] = *(const uint4*)&sH[r * 136 + c8];
        }
        __syncthreads();
    }
}

// ---- fill (+local 98-chunk scan, replaces scan2 dispatch) -----------------
// src_list[pos]=src (CSR order); attr_perm[pos]=bf16(attr[e]) (CSR order)
__global__ __launch_bounds__(256) void fill_kernel(
    const int* __restrict__ edge_index,
    const int* __restrict__ chunk_scan, const int* __restrict__ bsum_raw,
    int* __restrict__ counts, int* __restrict__ src_list,
    const float* __restrict__ attr, u16* __restrict__ attr_perm)
{
    __shared__ int sB[128];
    int tid = threadIdx.x;
    int v0 = 0;
    if (tid < 128) {
        v0 = (tid < N_CHUNKS) ? bsum_raw[tid] : 0;
        sB[tid] = v0;
    }
    __syncthreads();
    #pragma unroll
    for (int off = 1; off < 128; off <<= 1) {
        int t = (tid < 128 && tid >= off) ? sB[tid - off] : 0;
        __syncthreads();
        if (tid < 128) sB[tid] += t;
        __syncthreads();
    }
    if (tid < 128) sB[tid] -= v0;   // exclusive
    __syncthreads();

    int e = blockIdx.x * 256 + tid;
    if (e >= N_EDGES) return;
    int src = edge_index[e];
    int dst = edge_index[N_EDGES + e];
    int slot = atomicAdd(&counts[dst], -1) - 1;
    int pos = chunk_scan[dst] + sB[dst >> 10] + slot;
    src_list[pos] = src;
    float4 a0 = *(const float4*)&attr[(long)e * ED];
    float4 a1 = *(const float4*)&attr[(long)e * ED + 4];
    u32 w0 = bfpack(a0.x, a0.y);
    u32 w1 = bfpack(a0.z, a0.w);
    u32 w2 = bfpack(a1.x, a1.y);
    u32 w3 = bfpack(a1.z, a1.w);
    *(uint4*)&attr_perm[(long)pos * ED] = make_uint4(w0, w1, w2, w3);
}

// ---- edge MLP v3 (+finalize row_start prologue on blocks 0..391) ----------
// Linear stream: CSR-ordered attr in, linear e out. A-fragments from global
// (K=32 with cols 8..31 == 0). LDS = sH + small scan buf.
__global__ __launch_bounds__(256) void edge_mlp_mfma(
    const u16* __restrict__ attr_perm,
    const int* __restrict__ chunk_scan, const int* __restrict__ bsum_raw,
    int* __restrict__ row_start,
    const short8* __restrict__ pW1, const float* __restrict__ b1,
    const short8* __restrict__ pW2, const float* __restrict__ b2,
    u16* __restrict__ e_perm)
{
    __shared__ u16 sH[64 * 136];
    __shared__ int sB[128];
    int tid = threadIdx.x;

    if (blockIdx.x < 392) {   // finalize: row_start[i] = chunk_scan[i]+bsum[i>>10]
        int v0 = 0;
        if (tid < 128) {
            v0 = (tid < N_CHUNKS) ? bsum_raw[tid] : 0;
            sB[tid] = v0;
        }
        __syncthreads();
        #pragma unroll
        for (int off = 1; off < 128; off <<= 1) {
            int t = (tid < 128 && tid >= off) ? sB[tid - off] : 0;
            __syncthreads();
            if (tid < 128) sB[tid] += t;
            __syncthreads();
        }
        if (tid < 128) sB[tid] -= v0;
        __syncthreads();
        int i = blockIdx.x * 256 + tid;   // 392*256 = 100352 >= N_NODES+1
        if (i <= N_NODES) row_start[i] = chunk_scan[i] + sB[i >> 10];
        __syncthreads();
    }

    int w = tid >> 6, lane = tid & 63, quad = lane >> 4, n15 = lane & 15;
    short8 fW1[2];
    fW1[0] = pW1[(w * 2 + 0) * 64 + lane];
    fW1[1] = pW1[(w * 2 + 1) * 64 + lane];
    short8 fW2[4][2];
    #pragma unroll
    for (int kk = 0; kk < 4; kk++) {
        fW2[kk][0] = pW2[((w * 4 + kk) * 2 + 0) * 64 + lane];
        fW2[kk][1] = pW2[((w * 4 + kk) * 2 + 1) * 64 + lane];
    }
    float rb1[2] = { b1[w * 32 + n15], b1[w * 32 + 16 + n15] };
    float rb2[2] = { b2[w * 32 + n15], b2[w * 32 + 16 + n15] };
    const short8 zero8 = (short8){0,0,0,0,0,0,0,0};
    const int ntile = N_EDGES / 64;   // 9375 exact
    for (int tile = blockIdx.x; tile < ntile; tile += gridDim.x) {
        int row0 = tile * 64;
        short8 av[4];
        #pragma unroll
        for (int s = 0; s < 4; s++) {
            av[s] = zero8;
            if (quad == 0)
                av[s] = *(const short8*)&attr_perm[(long)(row0 + s * 16 + n15) * ED];
        }
        // GEMM1 (K=32, one step)
        f32x4 acc[4][2];
        #pragma unroll
        for (int s = 0; s < 4; s++) { acc[s][0] = (f32x4){0,0,0,0}; acc[s][1] = (f32x4){0,0,0,0}; }
        #pragma unroll
        for (int s = 0; s < 4; s++) {
            acc[s][0] = __builtin_amdgcn_mfma_f32_16x16x32_bf16(av[s], fW1[0], acc[s][0], 0, 0, 0);
            acc[s][1] = __builtin_amdgcn_mfma_f32_16x16x32_bf16(av[s], fW1[1], acc[s][1], 0, 0, 0);
        }
        #pragma unroll
        for (int s = 0; s < 4; s++)
            #pragma unroll
            for (int nt = 0; nt < 2; nt++) {
                int col = w * 32 + nt * 16 + n15;
                int rb = (s * 16 + quad * 4) * 136 + col;
                u32 p0 = bfpack(fmaxf(acc[s][nt][0] + rb1[nt], 0.0f),
                                fmaxf(acc[s][nt][1] + rb1[nt], 0.0f));
                u32 p1 = bfpack(fmaxf(acc[s][nt][2] + rb1[nt], 0.0f),
                                fmaxf(acc[s][nt][3] + rb1[nt], 0.0f));
                sH[rb]       = (u16)p0;
                sH[rb + 136] = (u16)(p0 >> 16);
                sH[rb + 272] = (u16)p1;
                sH[rb + 408] = (u16)(p1 >> 16);
            }
        __syncthreads();
        // GEMM2 (K=128)
        #pragma unroll
        for (int s = 0; s < 4; s++) { acc[s][0] = (f32x4){0,0,0,0}; acc[s][1] = (f32x4){0,0,0,0}; }
        #pragma unroll
        for (int kk = 0; kk < 4; kk++) {
            #pragma unroll
            for (int s = 0; s < 4; s++) {
                short8 a = *(const short8*)&sH[(s * 16 + n15) * 136 + kk * 32 + quad * 8];
                acc[s][0] = __builtin_amdgcn_mfma_f32_16x16x32_bf16(a, fW2[kk][0], acc[s][0], 0, 0, 0);
                acc[s][1] = __builtin_amdgcn_mfma_f32_16x16x32_bf16(a, fW2[kk][1], acc[s][1], 0, 0, 0);
            }
        }
        __syncthreads();
        #pragma unroll
        for (int s = 0; s < 4; s++)
            #pragma unroll
            for (int nt = 0; nt < 2; nt++) {
                int col = w * 32 + nt * 16 + n15;
                int rb = (s * 16 + quad * 4) * 136 + col;
                u32 p0 = bfpack(acc[s][nt][0] + rb2[nt], acc[s][nt][1] + rb2[nt]);
                u32 p1 = bfpack(acc[s][nt][2] + rb2[nt], acc[s][nt][3] + rb2[nt]);
                sH[rb]       = (u16)p0;
                sH[rb + 136] = (u16)(p0 >> 16);
                sH[rb + 272] = (u16)p1;
                sH[rb + 408] = (u16)(p1 >> 16);
            }
        __syncthreads();
        for (int idx = tid; idx < 64 * 16; idx += 256) {
            int r = idx >> 4, c8 = (idx & 15) << 3;
            *(uint4*)&e_perm[(long)(row0 + r) * H + c8] = *(const uint4*)&sH[r * 136 + c8];
        }
        __syncthreads();
    }
}

// ---- aggregate (r3-proven): 16-lane group per node, dwordx4 row loads -----
static __device__ __forceinline__ void acc8(float* a, u32x4 xv, u32x4 ev) {
    #pragma unroll
    for (int q = 0; q < 4; q++) {
        a[2 * q + 0] += fmaxf(bf2f(xv[q] & 0xffff) + bf2f(ev[q] & 0xffff), 0.0f);
        a[2 * q + 1] += fmaxf(bf2f(xv[q] >> 16)    + bf2f(ev[q] >> 16),    0.0f);
    }
}

__global__ __launch_bounds__(256) void aggregate_kernel(
    const int* __restrict__ row_start,
    const int* __restrict__ src_list,
    const u16* __restrict__ e_perm,
    const u16* __restrict__ x,
    u16* __restrict__ xs_out)
{
    int tid  = threadIdx.x;
    int lane = tid & 63;
    int l16  = lane & 15;
    int base = lane & 48;            // group base lane within wave
    int fo   = l16 * 8;              // 8 u16 cols per lane
    int n = blockIdx.x * 16 + (tid >> 4);   // exact: 6250*16 = 100000
    const u16* xb = x + fo;

    int beg = row_start[n];
    int end = row_start[n + 1];
    float a[8], b[8];
    #pragma unroll
    for (int q = 0; q < 8; q++) { a[q] = 0.0f; b[q] = 0.0f; }

    for (int j0 = beg; j0 < end; j0 += 16) {
        int m = min(16, end - j0);
        int sv = src_list[j0 + min(l16, m - 1)];
        const u16* ej = e_perm + (long)j0 * H + fo;
        int j = 0;
        for (; j + 2 <= m; j += 2) {
            int s0 = __shfl(sv, base | j);
            int s1 = __shfl(sv, base | (j + 1));
            u32x4 xv0 = *(const u32x4*)(xb + (long)s0 * H);
            u32x4 ev0 = *(const u32x4*)(ej + (long)(j + 0) * H);
            u32x4 xv1 = *(const u32x4*)(xb + (long)s1 * H);
            u32x4 ev1 = *(const u32x4*)(ej + (long)(j + 1) * H);
            acc8(a, xv0, ev0);
            acc8(b, xv1, ev1);
        }
        if (j < m) {
            int s0 = __shfl(sv, base | j);
            u32x4 xv0 = *(const u32x4*)(xb + (long)s0 * H);
            u32x4 ev0 = *(const u32x4*)(ej + (long)j * H);
            acc8(a, xv0, ev0);
        }
    }
    u32x4 xself = *(const u32x4*)(xb + (long)n * H);
    u32x4 out;
    #pragma unroll
    for (int q = 0; q < 4; q++) {
        float o0 = bf2f(xself[q] & 0xffff) + a[2 * q + 0] + b[2 * q + 0];
        float o1 = bf2f(xself[q] >> 16)    + a[2 * q + 1] + b[2 * q + 1];
        out[q] = bfpack(o0, o1);
    }
    *(u32x4*)&xs_out[(long)n * H + fo] = out;
}

// ---- conv MLP: 32-row tiles, single LDS buffer, high block count ----------
__global__ __launch_bounds__(256) void conv_mlp_mfma(
    const u16* __restrict__ xs,
    const short8* __restrict__ pW1, const float* __restrict__ b1,
    const short8* __restrict__ pW2, const float* __restrict__ b2,
    u16* __restrict__ x_out)
{
    __shared__ u16 sA[32 * 136];
    int tid = threadIdx.x;
    int w = tid >> 6, lane = tid & 63, quad = lane >> 4, n15 = lane & 15;
    short8 fW1[4][2], fW2[4][2];
    #pragma unroll
    for (int kk = 0; kk < 4; kk++) {
        fW1[kk][0] = pW1[((w * 4 + kk) * 2 + 0) * 64 + lane];
        fW1[kk][1] = pW1[((w * 4 + kk) * 2 + 1) * 64 + lane];
        fW2[kk][0] = pW2[((w * 4 + kk) * 2 + 0) * 64 + lane];
        fW2[kk][1] = pW2[((w * 4 + kk) * 2 + 1) * 64 + lane];
    }
    float rb1[2] = { b1[w * 32 + n15], b1[w * 32 + 16 + n15] };
    float rb2[2] = { b2[w * 32 + n15], b2[w * 32 + 16 + n15] };
    const int ntile = N_NODES / 32;   // 3125 exact
    for (int tile = blockIdx.x; tile < ntile; tile += gridDim.x) {
        long row0 = (long)tile * 32;
        for (int idx = tid; idx < 32 * 16; idx += 256) {
            int r = idx >> 4, c8 = (idx & 15) << 3;
            *(uint4*)&sA[r * 136 + c8] = *(const uint4*)&xs[(row0 + r) * H + c8];
        }
        __syncthreads();
        // GEMM1
        f32x4 acc[2][2];
        #pragma unroll
        for (int s = 0; s < 2; s++) { acc[s][0] = (f32x4){0,0,0,0}; acc[s][1] = (f32x4){0,0,0,0}; }
        #pragma unroll
        for (int kk = 0; kk < 4; kk++) {
            #pragma unroll
            for (int s = 0; s < 2; s++) {
                short8 a = *(const short8*)&sA[(s * 16 + n15) * 136 + kk * 32 + quad * 8];
                acc[s][0] = __builtin_amdgcn_mfma_f32_16x16x32_bf16(a, fW1[kk][0], acc[s][0], 0, 0, 0);
                acc[s][1] = __builtin_amdgcn_mfma_f32_16x16x32_bf16(a, fW1[kk][1], acc[s][1], 0, 0, 0);
            }
        }
        __syncthreads();   // all sA reads done
        #pragma unroll
        for (int s = 0; s < 2; s++)
            #pragma unroll
            for (int nt = 0; nt < 2; nt++) {
                int col = w * 32 + nt * 16 + n15;
                int rb = (s * 16 + quad * 4) * 136 + col;
                u32 p0 = bfpack(fmaxf(acc[s][nt][0] + rb1[nt], 0.0f),
                                fmaxf(acc[s][nt][1] + rb1[nt], 0.0f));
                u32 p1 = bfpack(fmaxf(acc[s][nt][2] + rb1[nt], 0.0f),
                                fmaxf(acc[s][nt][3] + rb1[nt], 0.0f));
                sA[rb]       = (u16)p0;
                sA[rb + 136] = (u16)(p0 >> 16);
                sA[rb + 272] = (u16)p1;
                sA[rb + 408] = (u16)(p1 >> 16);
            }
        __syncthreads();
        // GEMM2
        #pragma unroll
        for (int s = 0; s < 2; s++) { acc[s][0] = (f32x4){0,0,0,0}; acc[s][1] = (f32x4){0,0,0,0}; }
        #pragma unroll
        for (int kk = 0; kk < 4; kk++) {
            #pragma unroll
            for (int s = 0; s < 2; s++) {
                short8 a = *(const short8*)&sA[(s * 16 + n15) * 136 + kk * 32 + quad * 8];
                acc[s][0] = __builtin_amdgcn_mfma_f32_16x16x32_bf16(a, fW2[kk][0], acc[s][0], 0, 0, 0);
                acc[s][1] = __builtin_amdgcn_mfma_f32_16x16x32_bf16(a, fW2[kk][1], acc[s][1], 0, 0, 0);
            }
        }
        __syncthreads();   // all sA reads done
        #pragma unroll
        for (int s = 0; s < 2; s++)
            #pragma unroll
            for (int nt = 0; nt < 2; nt++) {
                int col = w * 32 + nt * 16 + n15;
                int rb = (s * 16 + quad * 4) * 136 + col;
                u32 p0 = bfpack(fmaxf(acc[s][nt][0] + rb2[nt], 0.0f),
                                fmaxf(acc[s][nt][1] + rb2[nt], 0.0f));
                u32 p1 = bfpack(fmaxf(acc[s][nt][2] + rb2[nt], 0.0f),
                                fmaxf(acc[s][nt][3] + rb2[nt], 0.0f));
                sA[rb]       = (u16)p0;
                sA[rb + 136] = (u16)(p0 >> 16);
                sA[rb + 272] = (u16)p1;
                sA[rb + 408] = (u16)(p1 >> 16);
            }
        __syncthreads();
        for (int idx = tid; idx < 32 * 16; idx += 256) {
            int r = idx >> 4, c8 = (idx & 15) << 3;
            *(uint4*)&x_out[(row0 + r) * H + c8] = *(const uint4*)&sA[r * 136 + c8];
        }
        __syncthreads();
    }
}

// ---------------- mean-pool: vectorized, high-TLP, segment flush -----------
__global__ __launch_bounds__(256) void pool_kernel(
    const u16* __restrict__ x, const int* __restrict__ batch,
    float* __restrict__ sums, float* __restrict__ cnt)
{
    int sg   = threadIdx.x >> 6;
    int lane = threadIdx.x & 63;
    int fo = lane * 2;
    const int nper = (N_NODES + gridDim.x - 1) / gridDim.x;
    int n0 = blockIdx.x * nper;
    int n1 = min(n0 + nper, N_NODES);
    int cur = -1;
    float a0 = 0.0f, a1 = 0.0f, c = 0.0f;
    for (int n = n0 + sg; n < n1; n += 4) {
        int b = batch[n];
        if (b != cur) {
            if (cur >= 0) {
                atomicAdd(&sums[cur * H + fo],     a0);
                atomicAdd(&sums[cur * H + fo + 1], a1);
                if (lane == 0) atomicAdd(&cnt[cur], c);
            }
            a0 = a1 = 0.0f; c = 0.0f; cur = b;
        }
        u32 xv = *(const u32*)&x[(long)n * H + fo];
        a0 += bf2f(xv & 0xffff);
        a1 += bf2f(xv >> 16);
        c += 1.0f;
    }
    if (cur >= 0) {
        atomicAdd(&sums[cur * H + fo],     a0);
        atomicAdd(&sums[cur * H + fo + 1], a1);
        if (lane == 0) atomicAdd(&cnt[cur], c);
    }
}

// ---------------- regressor ------------------------------------------------
__global__ __launch_bounds__(128) void regressor_kernel(
    const float* __restrict__ sums, const float* __restrict__ cnt,
    const float* __restrict__ depth,
    const float* __restrict__ w1, const float* __restrict__ b1,
    const float* __restrict__ w2, const float* __restrict__ b2,
    float* __restrict__ out)
{
    __shared__ float s_mean[H];
    __shared__ float s_red[2];
    int b = blockIdx.x;
    int j = threadIdx.x;
    float c = fmaxf(cnt[b], 1.0f);
    s_mean[j] = sums[b * H + j] / c;
    __syncthreads();
    float h = b1[j];
    #pragma unroll 8
    for (int k = 0; k < H; k++) h += s_mean[k] * w1[k * H + j];
    h += depth[b] * w1[H * H + j];
    h = fmaxf(h, 0.0f);
    float p = h * w2[j];
    #pragma unroll
    for (int off = 32; off >= 1; off >>= 1) p += __shfl_down(p, off, 64);
    if ((j & 63) == 0) s_red[j >> 6] = p;
    __syncthreads();
    if (j == 0) out[b] = s_red[0] + s_red[1] + b2[0];
}

extern "C" void kernel_launch(void* const* d_in, const int* in_sizes, int n_in,
                              void* d_out, int out_size, void* d_ws, size_t ws_size,
                              hipStream_t stream)
{
    const int*   ids   = (const int*)  d_in[0];
    const int*   eidx  = (const int*)  d_in[1];
    const float* eattr = (const float*)d_in[2];
    const int*   batch = (const int*)  d_in[3];
    const float* depth = (const float*)d_in[4];
    const float* id_w1 = (const float*)d_in[5];
    const float* id_b1 = (const float*)d_in[6];
    const float* id_w2 = (const float*)d_in[7];
    const float* id_b2 = (const float*)d_in[8];
    const float* ed_w1 = (const float*)d_in[9];
    const float* ed_b1 = (const float*)d_in[10];
    const float* ed_w2 = (const float*)d_in[11];
    const float* ed_b2 = (const float*)d_in[12];
    const float* c1_w1 = (const float*)d_in[13];
    const float* c1_b1 = (const float*)d_in[14];
    const float* c1_w2 = (const float*)d_in[15];
    const float* c1_b2 = (const float*)d_in[16];
    const float* c2_w1 = (const float*)d_in[17];
    const float* c2_b1 = (const float*)d_in[18];
    const float* c2_w2 = (const float*)d_in[19];
    const float* c2_b2 = (const float*)d_in[20];
    const float* rg_w1 = (const float*)d_in[21];
    const float* rg_b1 = (const float*)d_in[22];
    const float* rg_w2 = (const float*)d_in[23];
    const float* rg_b2 = (const float*)d_in[24];

    char* ws = (char*)d_ws;
    u16*   e_buf    = (u16*)  (ws);                      // 153,600,000 B (CSR order)
    u16*   x_buf    = (u16*)  (ws + 153600000);          //  25,600,000 B
    u16*   xs_buf   = (u16*)  (ws + 179200000);          //  25,600,000 B
    float* sums_buf = (float*)(ws + 204800000);          //     262,144 B
    float* cnt_buf  = (float*)(ws + 205062144);          //       2,048 B
    int*   counts   = (int*)  (ws + 205064192);          //     401,408 B
    int*   chunk_sc = (int*)  (ws + 205465600);          //     401,408 B
    int*   bsum_raw = (int*)  (ws + 205867008);          //         512 B
    int*   src_list = (int*)  (ws + 205868032);          //   2,400,000 B
    short8* ed_w1p  = (short8*)(ws + 208268032);         //       8,192 B
    short8* ed_w2p  = (short8*)(ws + 208276224);         //      32,768 B
    short8* c1_w1p  = (short8*)(ws + 208308992);
    short8* c1_w2p  = (short8*)(ws + 208341760);
    short8* c2_w1p  = (short8*)(ws + 208374528);
    short8* c2_w2p  = (short8*)(ws + 208407296);
    short8* id_w2p  = (short8*)(ws + 208440064);
    int*   row_start = counts;    // counts dead after fill; reuse
    u16*   attr_perm = xs_buf;    // alias: attr_perm dead before first agg write

    // zeroing (both memsets up front; no dependencies)
    hipMemsetAsync(counts, 0, 401408, stream);
    hipMemsetAsync(sums_buf, 0, (size_t)(NB * H + NB) * 4, stream);

    // pack (blocks 0..49) + hist (blocks 50..2393)
    pack_hist_kernel<<<50 + (N_EDGES + 255) / 256, 256, 0, stream>>>(
        ed_w1, ed_w2, c1_w1, c1_w2, c2_w1, c2_w2, id_w2,
        ed_w1p, ed_w2p, c1_w1p, c1_w2p, c2_w1p, c2_w2p, id_w2p,
        eidx, counts);

    // scan1 (blocks 0..97) + node MLP (blocks 98..865)
    scan_node_kernel<<<N_CHUNKS + 768, 256, 0, stream>>>(
        counts, chunk_sc, bsum_raw,
        ids, id_w1, id_b1, id_w2p, id_b2, x_buf);

    // fill (local bsum scan inside)
    fill_kernel<<<(N_EDGES + 255) / 256, 256, 0, stream>>>(
        eidx, chunk_sc, bsum_raw, counts, src_list, eattr, attr_perm);

    // edge MLP (+finalize row_start on blocks 0..391)
    edge_mlp_mfma<<<2048, 256, 0, stream>>>(
        attr_perm, chunk_sc, bsum_raw, row_start,
        ed_w1p, ed_b1, ed_w2p, ed_b2, e_buf);

    // conv 1
    aggregate_kernel<<<6250, 256, 0, stream>>>(row_start, src_list, e_buf, x_buf, xs_buf);
    conv_mlp_mfma<<<3125, 256, 0, stream>>>(xs_buf, c1_w1p, c1_b1, c1_w2p, c1_b2, x_buf);

    // conv 2
    aggregate_kernel<<<6250, 256, 0, stream>>>(row_start, src_list, e_buf, x_buf, xs_buf);
    conv_mlp_mfma<<<3125, 256, 0, stream>>>(xs_buf, c2_w1p, c2_b1, c2_w2p, c2_b2, x_buf);

    // pooling + regressor
    pool_kernel<<<2048, 256, 0, stream>>>(x_buf, batch, sums_buf, cnt_buf);
    regressor_kernel<<<NB, 128, 0, stream>>>(sums_buf, cnt_buf, depth,
                                             rg_w1, rg_b1, rg_w2, rg_b2, (float*)d_out);
}

// Round 9
// 370.331 us; speedup vs baseline: 1.5324x; 1.0620x over previous
//
#include <hip/hip_runtime.h>
#include <hip/hip_bf16.h>

#define N_NODES 100000
#define N_EDGES 600000
#define NB      512
#define H       128
#define ED      8
#define SCAN_CHUNK 1024
#define N_CHUNKS   98   // 98*1024 = 100352 >= N_NODES+1

typedef __attribute__((ext_vector_type(8))) short short8;
typedef __attribute__((ext_vector_type(4))) float f32x4;
typedef __attribute__((ext_vector_type(4))) unsigned int u32x4;
typedef unsigned short u16;
typedef unsigned int   u32;

static __device__ __forceinline__ u16 f2bf(float f) {
    u32 u = __float_as_uint(f);
    u32 r = u + 0x7fffu + ((u >> 16) & 1u);
    return (u16)(r >> 16);
}
static __device__ __forceinline__ float bf2f(u32 h) {
    return __uint_as_float(h << 16);
}
// packed f32->bf16 (RNE, same as f2bf): lo->bits[15:0], hi->bits[31:16]
static __device__ __forceinline__ u32 bfpack(float lo, float hi) {
    u32 r;
    asm("v_cvt_pk_bf16_f32 %0, %1, %2" : "=v"(r) : "v"(lo), "v"(hi));
    return r;
}

// ---- fused: weight pack (blocks 0..49) + degree histogram (blocks 50+) ----
__global__ __launch_bounds__(256) void pack_hist_kernel(
    const float* __restrict__ W0, const float* __restrict__ W1,
    const float* __restrict__ W2, const float* __restrict__ W3,
    const float* __restrict__ W4, const float* __restrict__ W5,
    const float* __restrict__ W6,
    short8* __restrict__ O0, short8* __restrict__ O1,
    short8* __restrict__ O2, short8* __restrict__ O3,
    short8* __restrict__ O4, short8* __restrict__ O5,
    short8* __restrict__ O6,
    const int* __restrict__ edge_index, int* __restrict__ counts)
{
    if (blockIdx.x >= 50) {
        int e = (blockIdx.x - 50) * 256 + threadIdx.x;
        if (e < N_EDGES) atomicAdd(&counts[edge_index[N_EDGES + e]], 1);
        return;
    }
    int gid = blockIdx.x * 256 + threadIdx.x;   // < 12800 exactly
    const float* W; short8* O; int Krows, kkmax, slot;
    if (gid < 512) { W = W0; O = O0; Krows = ED; kkmax = 1; slot = gid; }
    else {
        int m = (gid - 512) / 2048;
        slot = (gid - 512) % 2048;
        Krows = H; kkmax = 4;
        switch (m) {
            case 0: W = W1; O = O1; break;
            case 1: W = W2; O = O2; break;
            case 2: W = W3; O = O3; break;
            case 3: W = W4; O = O4; break;
            case 4: W = W5; O = O5; break;
            default: W = W6; O = O6; break;
        }
    }
    int lane = slot & 63;
    int t = slot >> 6;
    int nt = t & 1; t >>= 1;
    int kk = t % kkmax;
    int w  = t / kkmax;
    int quad = lane >> 4, n15 = lane & 15;
    int n = w * 32 + nt * 16 + n15;
    short8 v;
    #pragma unroll
    for (int j = 0; j < 8; j++) {
        int k = kk * 32 + quad * 8 + j;
        v[j] = (k < Krows) ? (short)f2bf(W[k * H + n]) : (short)0;
    }
    O[slot] = v;
}

// ---- fused: per-chunk scan (blocks 0..97, 256 thr x 4 elems) + node MLP ---
__global__ __launch_bounds__(256) void scan_node_kernel(
    const int* __restrict__ counts, int* __restrict__ chunk_scan,
    int* __restrict__ bsum_raw,
    const int* __restrict__ ids,
    const float* __restrict__ w1, const float* __restrict__ b1,
    const short8* __restrict__ pW2, const float* __restrict__ b2,
    u16* __restrict__ x_out)
{
    __shared__ u16 sH[64 * 136];
    __shared__ float s_x0[64];
    __shared__ int sS[256];
    int tid = threadIdx.x;

    if (blockIdx.x < N_CHUNKS) {
        // ---- scan1: 1024-elem chunk, 4 elems/thread ----
        int base = blockIdx.x * SCAN_CHUNK + tid * 4;
        int4 v = *(const int4*)&counts[base];
        int q0 = v.x, q1 = q0 + v.y, q2 = q1 + v.z, q3 = q2 + v.w;
        sS[tid] = q3;
        __syncthreads();
        #pragma unroll
        for (int off = 1; off < 256; off <<= 1) {
            int t = (tid >= off) ? sS[tid - off] : 0;
            __syncthreads();
            sS[tid] += t;
            __syncthreads();
        }
        int excl = sS[tid] - q3;
        int4 o;
        o.x = excl; o.y = excl + q0; o.z = excl + q1; o.w = excl + q2;
        *(int4*)&chunk_scan[base] = o;
        if (tid == 255) bsum_raw[blockIdx.x] = sS[255];
        return;
    }

    // ---- node MLP on blocks 98..865 (768 blocks) ----
    int bid = blockIdx.x - N_CHUNKS;
    int w = tid >> 6, lane = tid & 63, quad = lane >> 4, n15 = lane & 15;
    short8 fW2[4][2];
    #pragma unroll
    for (int kk = 0; kk < 4; kk++) {
        fW2[kk][0] = pW2[((w * 4 + kk) * 2 + 0) * 64 + lane];
        fW2[kk][1] = pW2[((w * 4 + kk) * 2 + 1) * 64 + lane];
    }
    float rb2[2] = { b2[w * 32 + n15], b2[w * 32 + 16 + n15] };
    float w1c = w1[tid & 127], b1c = b1[tid & 127];
    const int ntile = (N_NODES + 63) / 64;
    for (int tile = bid; tile < ntile; tile += 768) {
        int row0 = tile * 64;
        if (tid < 64) {
            int n = row0 + tid;
            float x0 = (n < N_NODES) ? (float)ids[n] / 281474976710655.0f : 0.0f;
            s_x0[tid] = fminf(fmaxf(x0, 0.0f), 1.0f);
        }
        __syncthreads();
        int half = tid >> 7, c = tid & 127;
        #pragma unroll
        for (int rr = 0; rr < 32; rr += 2) {
            int r = half + rr * 2;
            u32 p = bfpack(fmaxf(s_x0[r] * w1c + b1c, 0.0f),
                           fmaxf(s_x0[r + 2] * w1c + b1c, 0.0f));
            sH[r * 136 + c]       = (u16)p;
            sH[(r + 2) * 136 + c] = (u16)(p >> 16);
        }
        __syncthreads();
        f32x4 acc[4][2];
        #pragma unroll
        for (int s = 0; s < 4; s++) { acc[s][0] = (f32x4){0,0,0,0}; acc[s][1] = (f32x4){0,0,0,0}; }
        #pragma unroll
        for (int kk = 0; kk < 4; kk++) {
            #pragma unroll
            for (int s = 0; s < 4; s++) {
                short8 a = *(const short8*)&sH[(s * 16 + n15) * 136 + kk * 32 + quad * 8];
                acc[s][0] = __builtin_amdgcn_mfma_f32_16x16x32_bf16(a, fW2[kk][0], acc[s][0], 0, 0, 0);
                acc[s][1] = __builtin_amdgcn_mfma_f32_16x16x32_bf16(a, fW2[kk][1], acc[s][1], 0, 0, 0);
            }
        }
        __syncthreads();
        #pragma unroll
        for (int s = 0; s < 4; s++)
            #pragma unroll
            for (int nt = 0; nt < 2; nt++) {
                int col = w * 32 + nt * 16 + n15;
                int rb = (s * 16 + quad * 4) * 136 + col;
                u32 p0 = bfpack(acc[s][nt][0] + rb2[nt], acc[s][nt][1] + rb2[nt]);
                u32 p1 = bfpack(acc[s][nt][2] + rb2[nt], acc[s][nt][3] + rb2[nt]);
                sH[rb]       = (u16)p0;
                sH[rb + 136] = (u16)(p0 >> 16);
                sH[rb + 272] = (u16)p1;
                sH[rb + 408] = (u16)(p1 >> 16);
            }
        __syncthreads();
        for (int idx = tid; idx < 64 * 16; idx += 256) {
            int r = idx >> 4, c8 = (idx & 15) << 3;
            int n = row0 + r;
            if (n < N_NODES)
                *(uint4*)&x_out[(long)n * H + c8] = *(const uint4*)&sH[r * 136 + c8];
        }
        __syncthreads();
    }
}

// ---- fill (+local 98-chunk scan, replaces scan2 dispatch) -----------------
__global__ __launch_bounds__(256) void fill_kernel(
    const int* __restrict__ edge_index,
    const int* __restrict__ chunk_scan, const int* __restrict__ bsum_raw,
    int* __restrict__ counts, int* __restrict__ src_list,
    const float* __restrict__ attr, u16* __restrict__ attr_perm)
{
    __shared__ int sB[128];
    int tid = threadIdx.x;
    int v0 = 0;
    if (tid < 128) {
        v0 = (tid < N_CHUNKS) ? bsum_raw[tid] : 0;
        sB[tid] = v0;
    }
    __syncthreads();
    #pragma unroll
    for (int off = 1; off < 128; off <<= 1) {
        int t = (tid < 128 && tid >= off) ? sB[tid - off] : 0;
        __syncthreads();
        if (tid < 128) sB[tid] += t;
        __syncthreads();
    }
    if (tid < 128) sB[tid] -= v0;   // exclusive
    __syncthreads();

    int e = blockIdx.x * 256 + tid;
    if (e >= N_EDGES) return;
    int src = edge_index[e];
    int dst = edge_index[N_EDGES + e];
    int slot = atomicAdd(&counts[dst], -1) - 1;
    int pos = chunk_scan[dst] + sB[dst >> 10] + slot;
    src_list[pos] = src;
    float4 a0 = *(const float4*)&attr[(long)e * ED];
    float4 a1 = *(const float4*)&attr[(long)e * ED + 4];
    u32 w0 = bfpack(a0.x, a0.y);
    u32 w1 = bfpack(a0.z, a0.w);
    u32 w2 = bfpack(a1.x, a1.y);
    u32 w3 = bfpack(a1.z, a1.w);
    *(uint4*)&attr_perm[(long)pos * ED] = make_uint4(w0, w1, w2, w3);
}

// ---- edge MLP v3 (+finalize row_start prologue on blocks 0..391) ----------
__global__ __launch_bounds__(256) void edge_mlp_mfma(
    const u16* __restrict__ attr_perm,
    const int* __restrict__ chunk_scan, const int* __restrict__ bsum_raw,
    int* __restrict__ row_start,
    const short8* __restrict__ pW1, const float* __restrict__ b1,
    const short8* __restrict__ pW2, const float* __restrict__ b2,
    u16* __restrict__ e_perm)
{
    __shared__ u16 sH[64 * 136];
    __shared__ int sB[128];
    int tid = threadIdx.x;

    if (blockIdx.x < 392) {   // finalize: row_start[i] = chunk_scan[i]+bsum[i>>10]
        int v0 = 0;
        if (tid < 128) {
            v0 = (tid < N_CHUNKS) ? bsum_raw[tid] : 0;
            sB[tid] = v0;
        }
        __syncthreads();
        #pragma unroll
        for (int off = 1; off < 128; off <<= 1) {
            int t = (tid < 128 && tid >= off) ? sB[tid - off] : 0;
            __syncthreads();
            if (tid < 128) sB[tid] += t;
            __syncthreads();
        }
        if (tid < 128) sB[tid] -= v0;
        __syncthreads();
        int i = blockIdx.x * 256 + tid;   // 392*256 = 100352 >= N_NODES+1
        if (i <= N_NODES) row_start[i] = chunk_scan[i] + sB[i >> 10];
        __syncthreads();
    }

    int w = tid >> 6, lane = tid & 63, quad = lane >> 4, n15 = lane & 15;
    short8 fW1[2];
    fW1[0] = pW1[(w * 2 + 0) * 64 + lane];
    fW1[1] = pW1[(w * 2 + 1) * 64 + lane];
    short8 fW2[4][2];
    #pragma unroll
    for (int kk = 0; kk < 4; kk++) {
        fW2[kk][0] = pW2[((w * 4 + kk) * 2 + 0) * 64 + lane];
        fW2[kk][1] = pW2[((w * 4 + kk) * 2 + 1) * 64 + lane];
    }
    float rb1[2] = { b1[w * 32 + n15], b1[w * 32 + 16 + n15] };
    float rb2[2] = { b2[w * 32 + n15], b2[w * 32 + 16 + n15] };
    const short8 zero8 = (short8){0,0,0,0,0,0,0,0};
    const int ntile = N_EDGES / 64;   // 9375 exact
    for (int tile = blockIdx.x; tile < ntile; tile += gridDim.x) {
        int row0 = tile * 64;
        short8 av[4];
        #pragma unroll
        for (int s = 0; s < 4; s++) {
            av[s] = zero8;
            if (quad == 0)
                av[s] = *(const short8*)&attr_perm[(long)(row0 + s * 16 + n15) * ED];
        }
        // GEMM1 (K=32, one step)
        f32x4 acc[4][2];
        #pragma unroll
        for (int s = 0; s < 4; s++) { acc[s][0] = (f32x4){0,0,0,0}; acc[s][1] = (f32x4){0,0,0,0}; }
        #pragma unroll
        for (int s = 0; s < 4; s++) {
            acc[s][0] = __builtin_amdgcn_mfma_f32_16x16x32_bf16(av[s], fW1[0], acc[s][0], 0, 0, 0);
            acc[s][1] = __builtin_amdgcn_mfma_f32_16x16x32_bf16(av[s], fW1[1], acc[s][1], 0, 0, 0);
        }
        #pragma unroll
        for (int s = 0; s < 4; s++)
            #pragma unroll
            for (int nt = 0; nt < 2; nt++) {
                int col = w * 32 + nt * 16 + n15;
                int rb = (s * 16 + quad * 4) * 136 + col;
                u32 p0 = bfpack(fmaxf(acc[s][nt][0] + rb1[nt], 0.0f),
                                fmaxf(acc[s][nt][1] + rb1[nt], 0.0f));
                u32 p1 = bfpack(fmaxf(acc[s][nt][2] + rb1[nt], 0.0f),
                                fmaxf(acc[s][nt][3] + rb1[nt], 0.0f));
                sH[rb]       = (u16)p0;
                sH[rb + 136] = (u16)(p0 >> 16);
                sH[rb + 272] = (u16)p1;
                sH[rb + 408] = (u16)(p1 >> 16);
            }
        __syncthreads();
        // GEMM2 (K=128)
        #pragma unroll
        for (int s = 0; s < 4; s++) { acc[s][0] = (f32x4){0,0,0,0}; acc[s][1] = (f32x4){0,0,0,0}; }
        #pragma unroll
        for (int kk = 0; kk < 4; kk++) {
            #pragma unroll
            for (int s = 0; s < 4; s++) {
                short8 a = *(const short8*)&sH[(s * 16 + n15) * 136 + kk * 32 + quad * 8];
                acc[s][0] = __builtin_amdgcn_mfma_f32_16x16x32_bf16(a, fW2[kk][0], acc[s][0], 0, 0, 0);
                acc[s][1] = __builtin_amdgcn_mfma_f32_16x16x32_bf16(a, fW2[kk][1], acc[s][1], 0, 0, 0);
            }
        }
        __syncthreads();
        #pragma unroll
        for (int s = 0; s < 4; s++)
            #pragma unroll
            for (int nt = 0; nt < 2; nt++) {
                int col = w * 32 + nt * 16 + n15;
                int rb = (s * 16 + quad * 4) * 136 + col;
                u32 p0 = bfpack(acc[s][nt][0] + rb2[nt], acc[s][nt][1] + rb2[nt]);
                u32 p1 = bfpack(acc[s][nt][2] + rb2[nt], acc[s][nt][3] + rb2[nt]);
                sH[rb]       = (u16)p0;
                sH[rb + 136] = (u16)(p0 >> 16);
                sH[rb + 272] = (u16)p1;
                sH[rb + 408] = (u16)(p1 >> 16);
            }
        __syncthreads();
        for (int idx = tid; idx < 64 * 16; idx += 256) {
            int r = idx >> 4, c8 = (idx & 15) << 3;
            *(uint4*)&e_perm[(long)(row0 + r) * H + c8] = *(const uint4*)&sH[r * 136 + c8];
        }
        __syncthreads();
    }
}

// ---- fused GINE layer: r3-aggregate (barrier-free gather) + 16-row conv ---
// Gather: 16-lane group per node, 16 nodes/block, 6250 blocks (verbatim r8).
// Then ONE barrier and the block's 4 waves run the 2-layer MLP on its own
// 16x128 tile. Weights read from global per-use (L2-hit) to keep VGPR low.
static __device__ __forceinline__ void acc8(float* a, u32x4 xv, u32x4 ev) {
    #pragma unroll
    for (int q = 0; q < 4; q++) {
        a[2 * q + 0] += fmaxf(bf2f(xv[q] & 0xffff) + bf2f(ev[q] & 0xffff), 0.0f);
        a[2 * q + 1] += fmaxf(bf2f(xv[q] >> 16)    + bf2f(ev[q] >> 16),    0.0f);
    }
}

__global__ __launch_bounds__(256) void gine_fused(
    const int* __restrict__ row_start,
    const int* __restrict__ src_list,
    const u16* __restrict__ e_perm,
    const u16* __restrict__ x,
    const short8* __restrict__ pW1, const float* __restrict__ b1,
    const short8* __restrict__ pW2, const float* __restrict__ b2,
    u16* __restrict__ x_out)
{
    __shared__ u16 sA[16 * 136];
    int tid  = threadIdx.x;
    int lane = tid & 63;
    int l16  = lane & 15;
    int base = lane & 48;            // group base lane within wave
    int fo   = l16 * 8;              // 8 u16 cols per lane
    int r    = tid >> 4;             // local row 0..15
    int n    = blockIdx.x * 16 + r;  // exact: 6250*16 = 100000
    const u16* xb = x + fo;

    // ---------- gather phase (no barriers) ----------
    int beg = row_start[n];
    int end = row_start[n + 1];
    float a[8], b[8];
    #pragma unroll
    for (int q = 0; q < 8; q++) { a[q] = 0.0f; b[q] = 0.0f; }

    for (int j0 = beg; j0 < end; j0 += 16) {
        int m = min(16, end - j0);
        int sv = src_list[j0 + min(l16, m - 1)];
        const u16* ej = e_perm + (long)j0 * H + fo;
        int j = 0;
        for (; j + 2 <= m; j += 2) {
            int s0 = __shfl(sv, base | j);
            int s1 = __shfl(sv, base | (j + 1));
            u32x4 xv0 = *(const u32x4*)(xb + (long)s0 * H);
            u32x4 ev0 = *(const u32x4*)(ej + (long)(j + 0) * H);
            u32x4 xv1 = *(const u32x4*)(xb + (long)s1 * H);
            u32x4 ev1 = *(const u32x4*)(ej + (long)(j + 1) * H);
            acc8(a, xv0, ev0);
            acc8(b, xv1, ev1);
        }
        if (j < m) {
            int s0 = __shfl(sv, base | j);
            u32x4 xv0 = *(const u32x4*)(xb + (long)s0 * H);
            u32x4 ev0 = *(const u32x4*)(ej + (long)j * H);
            acc8(a, xv0, ev0);
        }
    }
    u32x4 xself = *(const u32x4*)(xb + (long)n * H);
    u32x4 xsrow;
    #pragma unroll
    for (int q = 0; q < 4; q++) {
        float o0 = bf2f(xself[q] & 0xffff) + a[2 * q + 0] + b[2 * q + 0];
        float o1 = bf2f(xself[q] >> 16)    + a[2 * q + 1] + b[2 * q + 1];
        xsrow[q] = bfpack(o0, o1);
    }
    *(uint4*)&sA[r * 136 + fo] = *(uint4*)&xsrow;   // xs row -> LDS (bf16)
    __syncthreads();

    // ---------- conv phase: 16x128 tile, 2 GEMMs ----------
    int w = tid >> 6, quad = lane >> 4, n15 = l16;
    float rb1[2] = { b1[w * 32 + n15], b1[w * 32 + 16 + n15] };
    float rb2[2] = { b2[w * 32 + n15], b2[w * 32 + 16 + n15] };
    // GEMM1 (weights streamed from global/L2 to keep VGPR low)
    f32x4 acc[2];
    acc[0] = (f32x4){0,0,0,0}; acc[1] = (f32x4){0,0,0,0};
    #pragma unroll
    for (int kk = 0; kk < 4; kk++) {
        short8 av = *(const short8*)&sA[n15 * 136 + kk * 32 + quad * 8];
        short8 w0 = pW1[((w * 4 + kk) * 2 + 0) * 64 + lane];
        short8 w1v = pW1[((w * 4 + kk) * 2 + 1) * 64 + lane];
        acc[0] = __builtin_amdgcn_mfma_f32_16x16x32_bf16(av, w0, acc[0], 0, 0, 0);
        acc[1] = __builtin_amdgcn_mfma_f32_16x16x32_bf16(av, w1v, acc[1], 0, 0, 0);
    }
    __syncthreads();   // sA reads done
    #pragma unroll
    for (int nt = 0; nt < 2; nt++) {
        int col = w * 32 + nt * 16 + n15;
        int rb = (quad * 4) * 136 + col;
        u32 p0 = bfpack(fmaxf(acc[nt][0] + rb1[nt], 0.0f),
                        fmaxf(acc[nt][1] + rb1[nt], 0.0f));
        u32 p1 = bfpack(fmaxf(acc[nt][2] + rb1[nt], 0.0f),
                        fmaxf(acc[nt][3] + rb1[nt], 0.0f));
        sA[rb]       = (u16)p0;
        sA[rb + 136] = (u16)(p0 >> 16);
        sA[rb + 272] = (u16)p1;
        sA[rb + 408] = (u16)(p1 >> 16);
    }
    __syncthreads();
    // GEMM2
    acc[0] = (f32x4){0,0,0,0}; acc[1] = (f32x4){0,0,0,0};
    #pragma unroll
    for (int kk = 0; kk < 4; kk++) {
        short8 av = *(const short8*)&sA[n15 * 136 + kk * 32 + quad * 8];
        short8 w0 = pW2[((w * 4 + kk) * 2 + 0) * 64 + lane];
        short8 w1v = pW2[((w * 4 + kk) * 2 + 1) * 64 + lane];
        acc[0] = __builtin_amdgcn_mfma_f32_16x16x32_bf16(av, w0, acc[0], 0, 0, 0);
        acc[1] = __builtin_amdgcn_mfma_f32_16x16x32_bf16(av, w1v, acc[1], 0, 0, 0);
    }
    __syncthreads();   // sA reads done
    #pragma unroll
    for (int nt = 0; nt < 2; nt++) {
        int col = w * 32 + nt * 16 + n15;
        int rb = (quad * 4) * 136 + col;
        u32 p0 = bfpack(fmaxf(acc[nt][0] + rb2[nt], 0.0f),
                        fmaxf(acc[nt][1] + rb2[nt], 0.0f));
        u32 p1 = bfpack(fmaxf(acc[nt][2] + rb2[nt], 0.0f),
                        fmaxf(acc[nt][3] + rb2[nt], 0.0f));
        sA[rb]       = (u16)p0;
        sA[rb + 136] = (u16)(p0 >> 16);
        sA[rb + 272] = (u16)p1;
        sA[rb + 408] = (u16)(p1 >> 16);
    }
    __syncthreads();
    // coalesced row store: 16 rows x 16 uint4 chunks = 256 = 1/thread
    {
        int rr = tid >> 4, c8 = (tid & 15) << 3;
        int nn = blockIdx.x * 16 + rr;
        *(uint4*)&x_out[(long)nn * H + c8] = *(const uint4*)&sA[rr * 136 + c8];
    }
}

// ---------------- mean-pool: vectorized, high-TLP, segment flush -----------
__global__ __launch_bounds__(256) void pool_kernel(
    const u16* __restrict__ x, const int* __restrict__ batch,
    float* __restrict__ sums, float* __restrict__ cnt)
{
    int sg   = threadIdx.x >> 6;
    int lane = threadIdx.x & 63;
    int fo = lane * 2;
    const int nper = (N_NODES + gridDim.x - 1) / gridDim.x;
    int n0 = blockIdx.x * nper;
    int n1 = min(n0 + nper, N_NODES);
    int cur = -1;
    float a0 = 0.0f, a1 = 0.0f, c = 0.0f;
    for (int n = n0 + sg; n < n1; n += 4) {
        int b = batch[n];
        if (b != cur) {
            if (cur >= 0) {
                atomicAdd(&sums[cur * H + fo],     a0);
                atomicAdd(&sums[cur * H + fo + 1], a1);
                if (lane == 0) atomicAdd(&cnt[cur], c);
            }
            a0 = a1 = 0.0f; c = 0.0f; cur = b;
        }
        u32 xv = *(const u32*)&x[(long)n * H + fo];
        a0 += bf2f(xv & 0xffff);
        a1 += bf2f(xv >> 16);
        c += 1.0f;
    }
    if (cur >= 0) {
        atomicAdd(&sums[cur * H + fo],     a0);
        atomicAdd(&sums[cur * H + fo + 1], a1);
        if (lane == 0) atomicAdd(&cnt[cur], c);
    }
}

// ---------------- regressor ------------------------------------------------
__global__ __launch_bounds__(128) void regressor_kernel(
    const float* __restrict__ sums, const float* __restrict__ cnt,
    const float* __restrict__ depth,
    const float* __restrict__ w1, const float* __restrict__ b1,
    const float* __restrict__ w2, const float* __restrict__ b2,
    float* __restrict__ out)
{
    __shared__ float s_mean[H];
    __shared__ float s_red[2];
    int b = blockIdx.x;
    int j = threadIdx.x;
    float c = fmaxf(cnt[b], 1.0f);
    s_mean[j] = sums[b * H + j] / c;
    __syncthreads();
    float h = b1[j];
    #pragma unroll 8
    for (int k = 0; k < H; k++) h += s_mean[k] * w1[k * H + j];
    h += depth[b] * w1[H * H + j];
    h = fmaxf(h, 0.0f);
    float p = h * w2[j];
    #pragma unroll
    for (int off = 32; off >= 1; off >>= 1) p += __shfl_down(p, off, 64);
    if ((j & 63) == 0) s_red[j >> 6] = p;
    __syncthreads();
    if (j == 0) out[b] = s_red[0] + s_red[1] + b2[0];
}

extern "C" void kernel_launch(void* const* d_in, const int* in_sizes, int n_in,
                              void* d_out, int out_size, void* d_ws, size_t ws_size,
                              hipStream_t stream)
{
    const int*   ids   = (const int*)  d_in[0];
    const int*   eidx  = (const int*)  d_in[1];
    const float* eattr = (const float*)d_in[2];
    const int*   batch = (const int*)  d_in[3];
    const float* depth = (const float*)d_in[4];
    const float* id_w1 = (const float*)d_in[5];
    const float* id_b1 = (const float*)d_in[6];
    const float* id_w2 = (const float*)d_in[7];
    const float* id_b2 = (const float*)d_in[8];
    const float* ed_w1 = (const float*)d_in[9];
    const float* ed_b1 = (const float*)d_in[10];
    const float* ed_w2 = (const float*)d_in[11];
    const float* ed_b2 = (const float*)d_in[12];
    const float* c1_w1 = (const float*)d_in[13];
    const float* c1_b1 = (const float*)d_in[14];
    const float* c1_w2 = (const float*)d_in[15];
    const float* c1_b2 = (const float*)d_in[16];
    const float* c2_w1 = (const float*)d_in[17];
    const float* c2_b1 = (const float*)d_in[18];
    const float* c2_w2 = (const float*)d_in[19];
    const float* c2_b2 = (const float*)d_in[20];
    const float* rg_w1 = (const float*)d_in[21];
    const float* rg_b1 = (const float*)d_in[22];
    const float* rg_w2 = (const float*)d_in[23];
    const float* rg_b2 = (const float*)d_in[24];

    char* ws = (char*)d_ws;
    u16*   e_buf    = (u16*)  (ws);                      // 153,600,000 B (CSR order)
    u16*   x_buf    = (u16*)  (ws + 153600000);          //  25,600,000 B
    u16*   xs_buf   = (u16*)  (ws + 179200000);          //  25,600,000 B (x ping-pong)
    float* sums_buf = (float*)(ws + 204800000);          //     262,144 B
    float* cnt_buf  = (float*)(ws + 205062144);          //       2,048 B
    int*   counts   = (int*)  (ws + 205064192);          //     401,408 B
    int*   chunk_sc = (int*)  (ws + 205465600);          //     401,408 B
    int*   bsum_raw = (int*)  (ws + 205867008);          //         512 B
    int*   src_list = (int*)  (ws + 205868032);          //   2,400,000 B
    short8* ed_w1p  = (short8*)(ws + 208268032);         //       8,192 B
    short8* ed_w2p  = (short8*)(ws + 208276224);         //      32,768 B
    short8* c1_w1p  = (short8*)(ws + 208308992);
    short8* c1_w2p  = (short8*)(ws + 208341760);
    short8* c2_w1p  = (short8*)(ws + 208374528);
    short8* c2_w2p  = (short8*)(ws + 208407296);
    short8* id_w2p  = (short8*)(ws + 208440064);
    int*   row_start = counts;    // counts dead after fill; reuse
    u16*   attr_perm = xs_buf;    // alias: attr_perm dead before gine1 write

    // zeroing (both memsets up front; no dependencies)
    hipMemsetAsync(counts, 0, 401408, stream);
    hipMemsetAsync(sums_buf, 0, (size_t)(NB * H + NB) * 4, stream);

    // pack (blocks 0..49) + hist (blocks 50..2393)
    pack_hist_kernel<<<50 + (N_EDGES + 255) / 256, 256, 0, stream>>>(
        ed_w1, ed_w2, c1_w1, c1_w2, c2_w1, c2_w2, id_w2,
        ed_w1p, ed_w2p, c1_w1p, c1_w2p, c2_w1p, c2_w2p, id_w2p,
        eidx, counts);

    // scan1 (blocks 0..97) + node MLP (blocks 98..865)
    scan_node_kernel<<<N_CHUNKS + 768, 256, 0, stream>>>(
        counts, chunk_sc, bsum_raw,
        ids, id_w1, id_b1, id_w2p, id_b2, x_buf);

    // fill (local bsum scan inside)
    fill_kernel<<<(N_EDGES + 255) / 256, 256, 0, stream>>>(
        eidx, chunk_sc, bsum_raw, counts, src_list, eattr, attr_perm);

    // edge MLP (+finalize row_start on blocks 0..391)
    edge_mlp_mfma<<<2048, 256, 0, stream>>>(
        attr_perm, chunk_sc, bsum_raw, row_start,
        ed_w1p, ed_b1, ed_w2p, ed_b2, e_buf);

    // layer 1 (fused aggregate + conv MLP): x_buf -> xs_buf
    gine_fused<<<6250, 256, 0, stream>>>(row_start, src_list, e_buf, x_buf,
                                         c1_w1p, c1_b1, c1_w2p, c1_b2, xs_buf);
    // layer 2: xs_buf -> x_buf
    gine_fused<<<6250, 256, 0, stream>>>(row_start, src_list, e_buf, xs_buf,
                                         c2_w1p, c2_b1, c2_w2p, c2_b2, x_buf);

    // pooling + regressor
    pool_kernel<<<2048, 256, 0, stream>>>(x_buf, batch, sums_buf, cnt_buf);
    regressor_kernel<<<NB, 128, 0, stream>>>(sums_buf, cnt_buf, depth,
                                             rg_w1, rg_b1, rg_w2, rg_b2, (float*)d_out);
}

// Round 10
// 358.896 us; speedup vs baseline: 1.5813x; 1.0319x over previous
//
#include <hip/hip_runtime.h>
#include <hip/hip_bf16.h>

#define N_NODES 100000
#define N_EDGES 600000
#define NB      512
#define H       128
#define ED      8
#define SCAN_CHUNK 1024
#define N_CHUNKS   98   // 98*1024 = 100352 >= N_NODES+1

typedef __attribute__((ext_vector_type(8))) short short8;
typedef __attribute__((ext_vector_type(4))) float f32x4;
typedef __attribute__((ext_vector_type(4))) unsigned int u32x4;
typedef unsigned short u16;
typedef unsigned int   u32;

static __device__ __forceinline__ u16 f2bf(float f) {
    u32 u = __float_as_uint(f);
    u32 r = u + 0x7fffu + ((u >> 16) & 1u);
    return (u16)(r >> 16);
}
static __device__ __forceinline__ float bf2f(u32 h) {
    return __uint_as_float(h << 16);
}
// packed f32->bf16 (RNE, same as f2bf): lo->bits[15:0], hi->bits[31:16]
static __device__ __forceinline__ u32 bfpack(float lo, float hi) {
    u32 r;
    asm("v_cvt_pk_bf16_f32 %0, %1, %2" : "=v"(r) : "v"(lo), "v"(hi));
    return r;
}

// ---- fused: weight pack (blocks 0..49) + degree histogram (blocks 50+) ----
__global__ __launch_bounds__(256) void pack_hist_kernel(
    const float* __restrict__ W0, const float* __restrict__ W1,
    const float* __restrict__ W2, const float* __restrict__ W3,
    const float* __restrict__ W4, const float* __restrict__ W5,
    const float* __restrict__ W6,
    short8* __restrict__ O0, short8* __restrict__ O1,
    short8* __restrict__ O2, short8* __restrict__ O3,
    short8* __restrict__ O4, short8* __restrict__ O5,
    short8* __restrict__ O6,
    const int* __restrict__ edge_index, int* __restrict__ counts)
{
    if (blockIdx.x >= 50) {
        int e = (blockIdx.x - 50) * 256 + threadIdx.x;
        if (e < N_EDGES) atomicAdd(&counts[edge_index[N_EDGES + e]], 1);
        return;
    }
    int gid = blockIdx.x * 256 + threadIdx.x;   // < 12800 exactly
    const float* W; short8* O; int Krows, kkmax, slot;
    if (gid < 512) { W = W0; O = O0; Krows = ED; kkmax = 1; slot = gid; }
    else {
        int m = (gid - 512) / 2048;
        slot = (gid - 512) % 2048;
        Krows = H; kkmax = 4;
        switch (m) {
            case 0: W = W1; O = O1; break;
            case 1: W = W2; O = O2; break;
            case 2: W = W3; O = O3; break;
            case 3: W = W4; O = O4; break;
            case 4: W = W5; O = O5; break;
            default: W = W6; O = O6; break;
        }
    }
    int lane = slot & 63;
    int t = slot >> 6;
    int nt = t & 1; t >>= 1;
    int kk = t % kkmax;
    int w  = t / kkmax;
    int quad = lane >> 4, n15 = lane & 15;
    int n = w * 32 + nt * 16 + n15;
    short8 v;
    #pragma unroll
    for (int j = 0; j < 8; j++) {
        int k = kk * 32 + quad * 8 + j;
        v[j] = (k < Krows) ? (short)f2bf(W[k * H + n]) : (short)0;
    }
    O[slot] = v;
}

// ---- fused: per-chunk scan (blocks 0..97, 256 thr x 4 elems) + node MLP ---
__global__ __launch_bounds__(256) void scan_node_kernel(
    const int* __restrict__ counts, int* __restrict__ chunk_scan,
    int* __restrict__ bsum_raw,
    const int* __restrict__ ids,
    const float* __restrict__ w1, const float* __restrict__ b1,
    const short8* __restrict__ pW2, const float* __restrict__ b2,
    u16* __restrict__ x_out)
{
    __shared__ u16 sH[64 * 136];
    __shared__ float s_x0[64];
    __shared__ int sS[256];
    int tid = threadIdx.x;

    if (blockIdx.x < N_CHUNKS) {
        // ---- scan1: 1024-elem chunk, 4 elems/thread ----
        int base = blockIdx.x * SCAN_CHUNK + tid * 4;
        int4 v = *(const int4*)&counts[base];
        int q0 = v.x, q1 = q0 + v.y, q2 = q1 + v.z, q3 = q2 + v.w;
        sS[tid] = q3;
        __syncthreads();
        #pragma unroll
        for (int off = 1; off < 256; off <<= 1) {
            int t = (tid >= off) ? sS[tid - off] : 0;
            __syncthreads();
            sS[tid] += t;
            __syncthreads();
        }
        int excl = sS[tid] - q3;
        int4 o;
        o.x = excl; o.y = excl + q0; o.z = excl + q1; o.w = excl + q2;
        *(int4*)&chunk_scan[base] = o;
        if (tid == 255) bsum_raw[blockIdx.x] = sS[255];
        return;
    }

    // ---- node MLP on blocks 98..865 (768 blocks) ----
    int bid = blockIdx.x - N_CHUNKS;
    int w = tid >> 6, lane = tid & 63, quad = lane >> 4, n15 = lane & 15;
    short8 fW2[4][2];
    #pragma unroll
    for (int kk = 0; kk < 4; kk++) {
        fW2[kk][0] = pW2[((w * 4 + kk) * 2 + 0) * 64 + lane];
        fW2[kk][1] = pW2[((w * 4 + kk) * 2 + 1) * 64 + lane];
    }
    float rb2[2] = { b2[w * 32 + n15], b2[w * 32 + 16 + n15] };
    float w1c = w1[tid & 127], b1c = b1[tid & 127];
    const int ntile = (N_NODES + 63) / 64;
    for (int tile = bid; tile < ntile; tile += 768) {
        int row0 = tile * 64;
        if (tid < 64) {
            int n = row0 + tid;
            float x0 = (n < N_NODES) ? (float)ids[n] / 281474976710655.0f : 0.0f;
            s_x0[tid] = fminf(fmaxf(x0, 0.0f), 1.0f);
        }
        __syncthreads();
        int half = tid >> 7, c = tid & 127;
        #pragma unroll
        for (int rr = 0; rr < 32; rr += 2) {
            int r = half + rr * 2;
            u32 p = bfpack(fmaxf(s_x0[r] * w1c + b1c, 0.0f),
                           fmaxf(s_x0[r + 2] * w1c + b1c, 0.0f));
            sH[r * 136 + c]       = (u16)p;
            sH[(r + 2) * 136 + c] = (u16)(p >> 16);
        }
        __syncthreads();
        f32x4 acc[4][2];
        #pragma unroll
        for (int s = 0; s < 4; s++) { acc[s][0] = (f32x4){0,0,0,0}; acc[s][1] = (f32x4){0,0,0,0}; }
        #pragma unroll
        for (int kk = 0; kk < 4; kk++) {
            #pragma unroll
            for (int s = 0; s < 4; s++) {
                short8 a = *(const short8*)&sH[(s * 16 + n15) * 136 + kk * 32 + quad * 8];
                acc[s][0] = __builtin_amdgcn_mfma_f32_16x16x32_bf16(a, fW2[kk][0], acc[s][0], 0, 0, 0);
                acc[s][1] = __builtin_amdgcn_mfma_f32_16x16x32_bf16(a, fW2[kk][1], acc[s][1], 0, 0, 0);
            }
        }
        __syncthreads();
        #pragma unroll
        for (int s = 0; s < 4; s++)
            #pragma unroll
            for (int nt = 0; nt < 2; nt++) {
                int col = w * 32 + nt * 16 + n15;
                int rb = (s * 16 + quad * 4) * 136 + col;
                u32 p0 = bfpack(acc[s][nt][0] + rb2[nt], acc[s][nt][1] + rb2[nt]);
                u32 p1 = bfpack(acc[s][nt][2] + rb2[nt], acc[s][nt][3] + rb2[nt]);
                sH[rb]       = (u16)p0;
                sH[rb + 136] = (u16)(p0 >> 16);
                sH[rb + 272] = (u16)p1;
                sH[rb + 408] = (u16)(p1 >> 16);
            }
        __syncthreads();
        for (int idx = tid; idx < 64 * 16; idx += 256) {
            int r = idx >> 4, c8 = (idx & 15) << 3;
            int n = row0 + r;
            if (n < N_NODES)
                *(uint4*)&x_out[(long)n * H + c8] = *(const uint4*)&sH[r * 136 + c8];
        }
        __syncthreads();
    }
}

// ---- fill (+local 98-chunk scan, replaces scan2 dispatch) -----------------
__global__ __launch_bounds__(256) void fill_kernel(
    const int* __restrict__ edge_index,
    const int* __restrict__ chunk_scan, const int* __restrict__ bsum_raw,
    int* __restrict__ counts, int* __restrict__ src_list,
    const float* __restrict__ attr, u16* __restrict__ attr_perm)
{
    __shared__ int sB[128];
    int tid = threadIdx.x;
    int v0 = 0;
    if (tid < 128) {
        v0 = (tid < N_CHUNKS) ? bsum_raw[tid] : 0;
        sB[tid] = v0;
    }
    __syncthreads();
    #pragma unroll
    for (int off = 1; off < 128; off <<= 1) {
        int t = (tid < 128 && tid >= off) ? sB[tid - off] : 0;
        __syncthreads();
        if (tid < 128) sB[tid] += t;
        __syncthreads();
    }
    if (tid < 128) sB[tid] -= v0;   // exclusive
    __syncthreads();

    int e = blockIdx.x * 256 + tid;
    if (e >= N_EDGES) return;
    int src = edge_index[e];
    int dst = edge_index[N_EDGES + e];
    int slot = atomicAdd(&counts[dst], -1) - 1;
    int pos = chunk_scan[dst] + sB[dst >> 10] + slot;
    src_list[pos] = src;
    float4 a0 = *(const float4*)&attr[(long)e * ED];
    float4 a1 = *(const float4*)&attr[(long)e * ED + 4];
    u32 w0 = bfpack(a0.x, a0.y);
    u32 w1 = bfpack(a0.z, a0.w);
    u32 w2 = bfpack(a1.x, a1.y);
    u32 w3 = bfpack(a1.z, a1.w);
    *(uint4*)&attr_perm[(long)pos * ED] = make_uint4(w0, w1, w2, w3);
}

// ---- edge MLP v3 (+finalize row_start prologue on blocks 0..391) ----------
__global__ __launch_bounds__(256) void edge_mlp_mfma(
    const u16* __restrict__ attr_perm,
    const int* __restrict__ chunk_scan, const int* __restrict__ bsum_raw,
    int* __restrict__ row_start,
    const short8* __restrict__ pW1, const float* __restrict__ b1,
    const short8* __restrict__ pW2, const float* __restrict__ b2,
    u16* __restrict__ e_perm)
{
    __shared__ u16 sH[64 * 136];
    __shared__ int sB[128];
    int tid = threadIdx.x;

    if (blockIdx.x < 392) {   // finalize: row_start[i] = chunk_scan[i]+bsum[i>>10]
        int v0 = 0;
        if (tid < 128) {
            v0 = (tid < N_CHUNKS) ? bsum_raw[tid] : 0;
            sB[tid] = v0;
        }
        __syncthreads();
        #pragma unroll
        for (int off = 1; off < 128; off <<= 1) {
            int t = (tid < 128 && tid >= off) ? sB[tid - off] : 0;
            __syncthreads();
            if (tid < 128) sB[tid] += t;
            __syncthreads();
        }
        if (tid < 128) sB[tid] -= v0;
        __syncthreads();
        int i = blockIdx.x * 256 + tid;   // 392*256 = 100352 >= N_NODES+1
        if (i <= N_NODES) row_start[i] = chunk_scan[i] + sB[i >> 10];
        __syncthreads();
    }

    int w = tid >> 6, lane = tid & 63, quad = lane >> 4, n15 = lane & 15;
    short8 fW1[2];
    fW1[0] = pW1[(w * 2 + 0) * 64 + lane];
    fW1[1] = pW1[(w * 2 + 1) * 64 + lane];
    short8 fW2[4][2];
    #pragma unroll
    for (int kk = 0; kk < 4; kk++) {
        fW2[kk][0] = pW2[((w * 4 + kk) * 2 + 0) * 64 + lane];
        fW2[kk][1] = pW2[((w * 4 + kk) * 2 + 1) * 64 + lane];
    }
    float rb1[2] = { b1[w * 32 + n15], b1[w * 32 + 16 + n15] };
    float rb2[2] = { b2[w * 32 + n15], b2[w * 32 + 16 + n15] };
    const short8 zero8 = (short8){0,0,0,0,0,0,0,0};
    const int ntile = N_EDGES / 64;   // 9375 exact
    for (int tile = blockIdx.x; tile < ntile; tile += gridDim.x) {
        int row0 = tile * 64;
        short8 av[4];
        #pragma unroll
        for (int s = 0; s < 4; s++) {
            av[s] = zero8;
            if (quad == 0)
                av[s] = *(const short8*)&attr_perm[(long)(row0 + s * 16 + n15) * ED];
        }
        // GEMM1 (K=32, one step)
        f32x4 acc[4][2];
        #pragma unroll
        for (int s = 0; s < 4; s++) { acc[s][0] = (f32x4){0,0,0,0}; acc[s][1] = (f32x4){0,0,0,0}; }
        #pragma unroll
        for (int s = 0; s < 4; s++) {
            acc[s][0] = __builtin_amdgcn_mfma_f32_16x16x32_bf16(av[s], fW1[0], acc[s][0], 0, 0, 0);
            acc[s][1] = __builtin_amdgcn_mfma_f32_16x16x32_bf16(av[s], fW1[1], acc[s][1], 0, 0, 0);
        }
        #pragma unroll
        for (int s = 0; s < 4; s++)
            #pragma unroll
            for (int nt = 0; nt < 2; nt++) {
                int col = w * 32 + nt * 16 + n15;
                int rb = (s * 16 + quad * 4) * 136 + col;
                u32 p0 = bfpack(fmaxf(acc[s][nt][0] + rb1[nt], 0.0f),
                                fmaxf(acc[s][nt][1] + rb1[nt], 0.0f));
                u32 p1 = bfpack(fmaxf(acc[s][nt][2] + rb1[nt], 0.0f),
                                fmaxf(acc[s][nt][3] + rb1[nt], 0.0f));
                sH[rb]       = (u16)p0;
                sH[rb + 136] = (u16)(p0 >> 16);
                sH[rb + 272] = (u16)p1;
                sH[rb + 408] = (u16)(p1 >> 16);
            }
        __syncthreads();
        // GEMM2 (K=128)
        #pragma unroll
        for (int s = 0; s < 4; s++) { acc[s][0] = (f32x4){0,0,0,0}; acc[s][1] = (f32x4){0,0,0,0}; }
        #pragma unroll
        for (int kk = 0; kk < 4; kk++) {
            #pragma unroll
            for (int s = 0; s < 4; s++) {
                short8 a = *(const short8*)&sH[(s * 16 + n15) * 136 + kk * 32 + quad * 8];
                acc[s][0] = __builtin_amdgcn_mfma_f32_16x16x32_bf16(a, fW2[kk][0], acc[s][0], 0, 0, 0);
                acc[s][1] = __builtin_amdgcn_mfma_f32_16x16x32_bf16(a, fW2[kk][1], acc[s][1], 0, 0, 0);
            }
        }
        __syncthreads();
        #pragma unroll
        for (int s = 0; s < 4; s++)
            #pragma unroll
            for (int nt = 0; nt < 2; nt++) {
                int col = w * 32 + nt * 16 + n15;
                int rb = (s * 16 + quad * 4) * 136 + col;
                u32 p0 = bfpack(acc[s][nt][0] + rb2[nt], acc[s][nt][1] + rb2[nt]);
                u32 p1 = bfpack(acc[s][nt][2] + rb2[nt], acc[s][nt][3] + rb2[nt]);
                sH[rb]       = (u16)p0;
                sH[rb + 136] = (u16)(p0 >> 16);
                sH[rb + 272] = (u16)p1;
                sH[rb + 408] = (u16)(p1 >> 16);
            }
        __syncthreads();
        for (int idx = tid; idx < 64 * 16; idx += 256) {
            int r = idx >> 4, c8 = (idx & 15) << 3;
            *(uint4*)&e_perm[(long)(row0 + r) * H + c8] = *(const uint4*)&sH[r * 136 + c8];
        }
        __syncthreads();
    }
}

// ---- fused GINE layer: barrier-free gather + 16-row conv (+opt. pool) -----
// Gather: 16-lane group per node, 16 nodes/block, 6250 blocks (verbatim r9).
// do_pool=1 (layer 2): skip x_out store; reduce tile into sums/cnt directly.
static __device__ __forceinline__ void acc8(float* a, u32x4 xv, u32x4 ev) {
    #pragma unroll
    for (int q = 0; q < 4; q++) {
        a[2 * q + 0] += fmaxf(bf2f(xv[q] & 0xffff) + bf2f(ev[q] & 0xffff), 0.0f);
        a[2 * q + 1] += fmaxf(bf2f(xv[q] >> 16)    + bf2f(ev[q] >> 16),    0.0f);
    }
}

__global__ __launch_bounds__(256) void gine_fused(
    const int* __restrict__ row_start,
    const int* __restrict__ src_list,
    const u16* __restrict__ e_perm,
    const u16* __restrict__ x,
    const short8* __restrict__ pW1, const float* __restrict__ b1,
    const short8* __restrict__ pW2, const float* __restrict__ b2,
    u16* __restrict__ x_out,
    const int* __restrict__ batch, float* __restrict__ sums,
    float* __restrict__ cnt, int do_pool)
{
    __shared__ u16 sA[16 * 136];
    __shared__ int sBt[16];
    int tid  = threadIdx.x;
    int lane = tid & 63;
    int l16  = lane & 15;
    int base = lane & 48;            // group base lane within wave
    int fo   = l16 * 8;              // 8 u16 cols per lane
    int r    = tid >> 4;             // local row 0..15
    int n    = blockIdx.x * 16 + r;  // exact: 6250*16 = 100000
    const u16* xb = x + fo;

    if (do_pool && tid < 16) sBt[tid] = batch[blockIdx.x * 16 + tid];

    // ---------- gather phase (no barriers) ----------
    int beg = row_start[n];
    int end = row_start[n + 1];
    float a[8], b[8];
    #pragma unroll
    for (int q = 0; q < 8; q++) { a[q] = 0.0f; b[q] = 0.0f; }

    for (int j0 = beg; j0 < end; j0 += 16) {
        int m = min(16, end - j0);
        int sv = src_list[j0 + min(l16, m - 1)];
        const u16* ej = e_perm + (long)j0 * H + fo;
        int j = 0;
        for (; j + 2 <= m; j += 2) {
            int s0 = __shfl(sv, base | j);
            int s1 = __shfl(sv, base | (j + 1));
            u32x4 xv0 = *(const u32x4*)(xb + (long)s0 * H);
            u32x4 ev0 = *(const u32x4*)(ej + (long)(j + 0) * H);
            u32x4 xv1 = *(const u32x4*)(xb + (long)s1 * H);
            u32x4 ev1 = *(const u32x4*)(ej + (long)(j + 1) * H);
            acc8(a, xv0, ev0);
            acc8(b, xv1, ev1);
        }
        if (j < m) {
            int s0 = __shfl(sv, base | j);
            u32x4 xv0 = *(const u32x4*)(xb + (long)s0 * H);
            u32x4 ev0 = *(const u32x4*)(ej + (long)j * H);
            acc8(a, xv0, ev0);
        }
    }
    u32x4 xself = *(const u32x4*)(xb + (long)n * H);
    u32x4 xsrow;
    #pragma unroll
    for (int q = 0; q < 4; q++) {
        float o0 = bf2f(xself[q] & 0xffff) + a[2 * q + 0] + b[2 * q + 0];
        float o1 = bf2f(xself[q] >> 16)    + a[2 * q + 1] + b[2 * q + 1];
        xsrow[q] = bfpack(o0, o1);
    }
    *(uint4*)&sA[r * 136 + fo] = *(uint4*)&xsrow;   // xs row -> LDS (bf16)
    __syncthreads();

    // ---------- conv phase: 16x128 tile, 2 GEMMs ----------
    int w = tid >> 6, quad = lane >> 4, n15 = l16;
    float rb1[2] = { b1[w * 32 + n15], b1[w * 32 + 16 + n15] };
    float rb2[2] = { b2[w * 32 + n15], b2[w * 32 + 16 + n15] };
    // GEMM1 (weights streamed from global/L2 to keep VGPR low)
    f32x4 acc[2];
    acc[0] = (f32x4){0,0,0,0}; acc[1] = (f32x4){0,0,0,0};
    #pragma unroll
    for (int kk = 0; kk < 4; kk++) {
        short8 av = *(const short8*)&sA[n15 * 136 + kk * 32 + quad * 8];
        short8 w0 = pW1[((w * 4 + kk) * 2 + 0) * 64 + lane];
        short8 w1v = pW1[((w * 4 + kk) * 2 + 1) * 64 + lane];
        acc[0] = __builtin_amdgcn_mfma_f32_16x16x32_bf16(av, w0, acc[0], 0, 0, 0);
        acc[1] = __builtin_amdgcn_mfma_f32_16x16x32_bf16(av, w1v, acc[1], 0, 0, 0);
    }
    __syncthreads();   // sA reads done
    #pragma unroll
    for (int nt = 0; nt < 2; nt++) {
        int col = w * 32 + nt * 16 + n15;
        int rb = (quad * 4) * 136 + col;
        u32 p0 = bfpack(fmaxf(acc[nt][0] + rb1[nt], 0.0f),
                        fmaxf(acc[nt][1] + rb1[nt], 0.0f));
        u32 p1 = bfpack(fmaxf(acc[nt][2] + rb1[nt], 0.0f),
                        fmaxf(acc[nt][3] + rb1[nt], 0.0f));
        sA[rb]       = (u16)p0;
        sA[rb + 136] = (u16)(p0 >> 16);
        sA[rb + 272] = (u16)p1;
        sA[rb + 408] = (u16)(p1 >> 16);
    }
    __syncthreads();
    // GEMM2
    acc[0] = (f32x4){0,0,0,0}; acc[1] = (f32x4){0,0,0,0};
    #pragma unroll
    for (int kk = 0; kk < 4; kk++) {
        short8 av = *(const short8*)&sA[n15 * 136 + kk * 32 + quad * 8];
        short8 w0 = pW2[((w * 4 + kk) * 2 + 0) * 64 + lane];
        short8 w1v = pW2[((w * 4 + kk) * 2 + 1) * 64 + lane];
        acc[0] = __builtin_amdgcn_mfma_f32_16x16x32_bf16(av, w0, acc[0], 0, 0, 0);
        acc[1] = __builtin_amdgcn_mfma_f32_16x16x32_bf16(av, w1v, acc[1], 0, 0, 0);
    }
    __syncthreads();   // sA reads done
    #pragma unroll
    for (int nt = 0; nt < 2; nt++) {
        int col = w * 32 + nt * 16 + n15;
        int rb = (quad * 4) * 136 + col;
        u32 p0 = bfpack(fmaxf(acc[nt][0] + rb2[nt], 0.0f),
                        fmaxf(acc[nt][1] + rb2[nt], 0.0f));
        u32 p1 = bfpack(fmaxf(acc[nt][2] + rb2[nt], 0.0f),
                        fmaxf(acc[nt][3] + rb2[nt], 0.0f));
        sA[rb]       = (u16)p0;
        sA[rb + 136] = (u16)(p0 >> 16);
        sA[rb + 272] = (u16)p1;
        sA[rb + 408] = (u16)(p1 >> 16);
    }
    __syncthreads();
    if (!do_pool) {
        // coalesced row store: 16 rows x 16 uint4 chunks = 256 = 1/thread
        int rr = tid >> 4, c8 = (tid & 15) << 3;
        int nn = blockIdx.x * 16 + rr;
        *(uint4*)&x_out[(long)nn * H + c8] = *(const uint4*)&sA[rr * 136 + c8];
    } else {
        // pool epilogue: column-wise segment reduce over the 16-row tile
        if (tid < 128) {
            int c = tid;
            float acc2 = 0.0f;
            int cur = sBt[0];
            #pragma unroll 4
            for (int rr = 0; rr < 16; rr++) {
                int bb = sBt[rr];
                if (bb != cur) {
                    atomicAdd(&sums[cur * H + c], acc2);
                    acc2 = 0.0f; cur = bb;
                }
                acc2 += bf2f((u32)sA[rr * 136 + c]);
            }
            atomicAdd(&sums[cur * H + c], acc2);
        } else if (tid == 128) {
            int cur = sBt[0];
            float cc = 0.0f;
            for (int rr = 0; rr < 16; rr++) {
                int bb = sBt[rr];
                if (bb != cur) {
                    atomicAdd(&cnt[cur], cc);
                    cc = 0.0f; cur = bb;
                }
                cc += 1.0f;
            }
            atomicAdd(&cnt[cur], cc);
        }
    }
}

// ---------------- regressor ------------------------------------------------
__global__ __launch_bounds__(128) void regressor_kernel(
    const float* __restrict__ sums, const float* __restrict__ cnt,
    const float* __restrict__ depth,
    const float* __restrict__ w1, const float* __restrict__ b1,
    const float* __restrict__ w2, const float* __restrict__ b2,
    float* __restrict__ out)
{
    __shared__ float s_mean[H];
    __shared__ float s_red[2];
    int b = blockIdx.x;
    int j = threadIdx.x;
    float c = fmaxf(cnt[b], 1.0f);
    s_mean[j] = sums[b * H + j] / c;
    __syncthreads();
    float h = b1[j];
    #pragma unroll 8
    for (int k = 0; k < H; k++) h += s_mean[k] * w1[k * H + j];
    h += depth[b] * w1[H * H + j];
    h = fmaxf(h, 0.0f);
    float p = h * w2[j];
    #pragma unroll
    for (int off = 32; off >= 1; off >>= 1) p += __shfl_down(p, off, 64);
    if ((j & 63) == 0) s_red[j >> 6] = p;
    __syncthreads();
    if (j == 0) out[b] = s_red[0] + s_red[1] + b2[0];
}

extern "C" void kernel_launch(void* const* d_in, const int* in_sizes, int n_in,
                              void* d_out, int out_size, void* d_ws, size_t ws_size,
                              hipStream_t stream)
{
    const int*   ids   = (const int*)  d_in[0];
    const int*   eidx  = (const int*)  d_in[1];
    const float* eattr = (const float*)d_in[2];
    const int*   batch = (const int*)  d_in[3];
    const float* depth = (const float*)d_in[4];
    const float* id_w1 = (const float*)d_in[5];
    const float* id_b1 = (const float*)d_in[6];
    const float* id_w2 = (const float*)d_in[7];
    const float* id_b2 = (const float*)d_in[8];
    const float* ed_w1 = (const float*)d_in[9];
    const float* ed_b1 = (const float*)d_in[10];
    const float* ed_w2 = (const float*)d_in[11];
    const float* ed_b2 = (const float*)d_in[12];
    const float* c1_w1 = (const float*)d_in[13];
    const float* c1_b1 = (const float*)d_in[14];
    const float* c1_w2 = (const float*)d_in[15];
    const float* c1_b2 = (const float*)d_in[16];
    const float* c2_w1 = (const float*)d_in[17];
    const float* c2_b1 = (const float*)d_in[18];
    const float* c2_w2 = (const float*)d_in[19];
    const float* c2_b2 = (const float*)d_in[20];
    const float* rg_w1 = (const float*)d_in[21];
    const float* rg_b1 = (const float*)d_in[22];
    const float* rg_w2 = (const float*)d_in[23];
    const float* rg_b2 = (const float*)d_in[24];

    char* ws = (char*)d_ws;
    u16*   e_buf    = (u16*)  (ws);                      // 153,600,000 B (CSR order)
    u16*   x_buf    = (u16*)  (ws + 153600000);          //  25,600,000 B
    u16*   xs_buf   = (u16*)  (ws + 179200000);          //  25,600,000 B (x ping-pong)
    float* sums_buf = (float*)(ws + 204800000);          //     262,144 B
    float* cnt_buf  = (float*)(ws + 205062144);          //       2,048 B
    int*   counts   = (int*)  (ws + 205064192);          //     401,408 B
    int*   chunk_sc = (int*)  (ws + 205465600);          //     401,408 B
    int*   bsum_raw = (int*)  (ws + 205867008);          //         512 B
    int*   src_list = (int*)  (ws + 205868032);          //   2,400,000 B
    short8* ed_w1p  = (short8*)(ws + 208268032);         //       8,192 B
    short8* ed_w2p  = (short8*)(ws + 208276224);         //      32,768 B
    short8* c1_w1p  = (short8*)(ws + 208308992);
    short8* c1_w2p  = (short8*)(ws + 208341760);
    short8* c2_w1p  = (short8*)(ws + 208374528);
    short8* c2_w2p  = (short8*)(ws + 208407296);
    short8* id_w2p  = (short8*)(ws + 208440064);
    int*   row_start = counts;    // counts dead after fill; reuse
    u16*   attr_perm = xs_buf;    // alias: attr_perm dead before gine1 write

    // zeroing (both memsets up front; no dependencies)
    hipMemsetAsync(counts, 0, 401408, stream);
    hipMemsetAsync(sums_buf, 0, (size_t)(NB * H + NB) * 4, stream);

    // pack (blocks 0..49) + hist (blocks 50..2393)
    pack_hist_kernel<<<50 + (N_EDGES + 255) / 256, 256, 0, stream>>>(
        ed_w1, ed_w2, c1_w1, c1_w2, c2_w1, c2_w2, id_w2,
        ed_w1p, ed_w2p, c1_w1p, c1_w2p, c2_w1p, c2_w2p, id_w2p,
        eidx, counts);

    // scan1 (blocks 0..97) + node MLP (blocks 98..865)
    scan_node_kernel<<<N_CHUNKS + 768, 256, 0, stream>>>(
        counts, chunk_sc, bsum_raw,
        ids, id_w1, id_b1, id_w2p, id_b2, x_buf);

    // fill (local bsum scan inside)
    fill_kernel<<<(N_EDGES + 255) / 256, 256, 0, stream>>>(
        eidx, chunk_sc, bsum_raw, counts, src_list, eattr, attr_perm);

    // edge MLP (+finalize row_start on blocks 0..391)
    edge_mlp_mfma<<<2048, 256, 0, stream>>>(
        attr_perm, chunk_sc, bsum_raw, row_start,
        ed_w1p, ed_b1, ed_w2p, ed_b2, e_buf);

    // layer 1 (fused aggregate + conv MLP): x_buf -> xs_buf
    gine_fused<<<6250, 256, 0, stream>>>(row_start, src_list, e_buf, x_buf,
                                         c1_w1p, c1_b1, c1_w2p, c1_b2, xs_buf,
                                         batch, sums_buf, cnt_buf, 0);
    // layer 2 (+fused mean-pool): xs_buf -> sums/cnt directly
    gine_fused<<<6250, 256, 0, stream>>>(row_start, src_list, e_buf, xs_buf,
                                         c2_w1p, c2_b1, c2_w2p, c2_b2, x_buf,
                                         batch, sums_buf, cnt_buf, 1);

    // regressor
    regressor_kernel<<<NB, 128, 0, stream>>>(sums_buf, cnt_buf, depth,
                                             rg_w1, rg_b1, rg_w2, rg_b2, (float*)d_out);
}